// Round 1
// baseline (2639.020 us; speedup 1.0000x reference)
//
#include <hip/hip_runtime.h>
#include <math.h>

#define NN 30000
#define NE 480000

// ---------------- CSR build (by dst) ----------------
__global__ void k_count(const int* __restrict__ dst, int* __restrict__ cnt) {
    int e = blockIdx.x * 256 + threadIdx.x;
    if (e < NE) atomicAdd(&cnt[dst[e]], 1);
}

__global__ __launch_bounds__(1024) void k_scan(const int* __restrict__ cnt,
                                               int* __restrict__ off,
                                               int* __restrict__ cur) {
    __shared__ int s[1024];
    __shared__ int sbase;
    int tid = threadIdx.x;
    if (tid == 0) sbase = 0;
    __syncthreads();
    for (int start = 0; start < NN; start += 1024) {
        int i = start + tid;
        int v = (i < NN) ? cnt[i] : 0;
        s[tid] = v;
        __syncthreads();
        for (int d = 1; d < 1024; d <<= 1) {
            int t = (tid >= d) ? s[tid - d] : 0;
            __syncthreads();
            s[tid] += t;
            __syncthreads();
        }
        int base = sbase;
        int excl = base + s[tid] - v;
        if (i < NN) { off[i] = excl; cur[i] = excl; }
        __syncthreads();
        if (tid == 0) sbase = base + s[1023];
        __syncthreads();
    }
    if (tid == 0) off[NN] = sbase;
}

__global__ void k_fill(const int* __restrict__ dst, int* __restrict__ cur,
                       int* __restrict__ eid) {
    int e = blockIdx.x * 256 + threadIdx.x;
    if (e < NE) {
        int p = atomicAdd(&cur[dst[e]], 1);
        eid[p] = e;
    }
}

// ---------------- layer1: hn1[n] = sum of efeats over in-edges ----------------
__global__ void k_agg_ef(const float* __restrict__ ef, const int* __restrict__ off,
                         const int* __restrict__ eid, float* __restrict__ hn1) {
    int w = (blockIdx.x * 256 + threadIdx.x) >> 6;
    int lane = threadIdx.x & 63;
    if (w >= NN) return;
    int s0 = off[w], s1 = off[w + 1];
    float acc = 0.f;
    for (int i = s0; i < s1; ++i) {
        int e = eid[i];
        acc += ef[(size_t)e * 64 + lane];
    }
    hn1[(size_t)w * 64 + lane] = acc;
}

// ---------------- node projections, layer1: P1[n][0:128]=hp1, [128:256]=pa1, [256:384]=pc1
__global__ __launch_bounds__(256) void k_nodeproj1(
        const float* __restrict__ hn1, const float* __restrict__ Wn1,
        const float* __restrict__ b1, const float* __restrict__ We1,
        float* __restrict__ P1) {
    __shared__ float Wl[384 * 68];
    __shared__ float Al[32 * 64];
    int tid = threadIdx.x;
    for (int t = tid; t < 384 * 16; t += 256) {
        int o = t >> 4, k4 = (t & 15) * 4;
        const float* sp;
        if (o < 128)      sp = &Wn1[o * 64 + k4];
        else if (o < 256) sp = &We1[(size_t)(o - 128) * 192 + k4];
        else              sp = &We1[(size_t)(o - 256) * 192 + 128 + k4];
        *(float4*)&Wl[o * 68 + k4] = *(const float4*)sp;
    }
    int nb = blockIdx.x * 32;
    for (int t = tid; t < 32 * 16; t += 256) {
        int r = t >> 4, k4 = (t & 15) * 4;
        int n = nb + r;
        float4 v = make_float4(0.f, 0.f, 0.f, 0.f);
        if (n < NN) v = *(const float4*)&hn1[(size_t)n * 64 + k4];
        *(float4*)&Al[r * 64 + k4] = v;
    }
    __syncthreads();
    int q = tid & 31, rg = tid >> 5;
    float acc[4][12];
    for (int i = 0; i < 4; ++i)
        for (int j = 0; j < 12; ++j) acc[i][j] = 0.f;
    for (int k4 = 0; k4 < 64; k4 += 4) {
        float4 a[4];
#pragma unroll
        for (int i = 0; i < 4; ++i) a[i] = *(float4*)&Al[(rg * 4 + i) * 64 + k4];
#pragma unroll
        for (int j = 0; j < 12; ++j) {
            float4 wv = *(float4*)&Wl[(q + 32 * j) * 68 + k4];
#pragma unroll
            for (int i = 0; i < 4; ++i)
                acc[i][j] += a[i].x * wv.x + a[i].y * wv.y + a[i].z * wv.z + a[i].w * wv.w;
        }
    }
    for (int i = 0; i < 4; ++i) {
        int n = nb + rg * 4 + i;
        if (n >= NN) continue;
        for (int j = 0; j < 12; ++j) {
            int o = q + 32 * j;
            float v = acc[i][j] + (o < 128 ? b1[o] : 0.f);
            P1[(size_t)n * 384 + o] = v;
        }
    }
}

// ---------------- edge GEMM layer1: he1 = elu(leaky(ef@Wb1.T + pa1[src] + pc1[dst])), a1
__global__ __launch_bounds__(256) void k_gemm1(
        const float* __restrict__ ef, const int* __restrict__ src,
        const int* __restrict__ dst, const float* __restrict__ We1,
        const float* __restrict__ Wa1, const float* __restrict__ P1,
        float* __restrict__ he1, float* __restrict__ a1) {
    __shared__ float Wl[128 * 68];
    __shared__ float Al[64 * 64];
    __shared__ float aacc[64 * 4];
    int tid = threadIdx.x;
    for (int t = tid; t < 128 * 16; t += 256) {
        int o = t >> 4, k4 = (t & 15) * 4;
        *(float4*)&Wl[o * 68 + k4] = *(const float4*)&We1[(size_t)o * 192 + 64 + k4];
    }
    int eb = blockIdx.x * 64;
    for (int t = tid; t < 64 * 16; t += 256) {
        int r = t >> 4, k4 = (t & 15) * 4;
        *(float4*)&Al[r * 64 + k4] = *(const float4*)&ef[(size_t)(eb + r) * 64 + k4];
    }
    aacc[tid] = 0.f;
    __syncthreads();
    int q = tid & 31, rg = tid >> 5;
    float acc[8][4];
    for (int i = 0; i < 8; ++i)
        for (int j = 0; j < 4; ++j) acc[i][j] = 0.f;
    for (int k4 = 0; k4 < 64; k4 += 4) {
        float4 a[8];
#pragma unroll
        for (int i = 0; i < 8; ++i) a[i] = *(float4*)&Al[(rg * 8 + i) * 64 + k4];
#pragma unroll
        for (int j = 0; j < 4; ++j) {
            float4 wv = *(float4*)&Wl[(q + 32 * j) * 68 + k4];
#pragma unroll
            for (int i = 0; i < 8; ++i)
                acc[i][j] += a[i].x * wv.x + a[i].y * wv.y + a[i].z * wv.z + a[i].w * wv.w;
        }
    }
    float was = Wa1[q] + Wa1[32 + q] + Wa1[64 + q] + Wa1[96 + q];
    for (int i = 0; i < 8; ++i) {
        int e = eb + rg * 8 + i;
        int s = src[e], d = dst[e];
        const float* pa = &P1[(size_t)s * 384 + 128];
        const float* pc = &P1[(size_t)d * 384 + 256];
        for (int j = 0; j < 4; ++j) {
            int o = q + 32 * j;
            float f = acc[i][j] + pa[o] + pc[o];
            f = (f > 0.f) ? f : 0.01f * f;
            atomicAdd(&aacc[(rg * 8 + i) * 4 + j], f * was);
            float el = (f > 0.f) ? f : expm1f(f);
            he1[(size_t)e * 128 + o] = el;
        }
    }
    __syncthreads();
    {
        int r = tid >> 2, h = tid & 3;
        a1[(size_t)(eb + r) * 4 + h] = aacc[tid];
    }
}

// ---------------- segment softmax + weighted aggregate, layer1 ----------------
__global__ void k_agg1(const float* __restrict__ a1, const int* __restrict__ off,
                       const int* __restrict__ eid, const int* __restrict__ src,
                       const float* __restrict__ P1, float* __restrict__ hn1o) {
    int w = (blockIdx.x * 256 + threadIdx.x) >> 6;
    int lane = threadIdx.x & 63;
    if (w >= NN) return;
    int s0 = off[w], s1 = off[w + 1];
    float m[4] = {-INFINITY, -INFINITY, -INFINITY, -INFINITY};
    for (int i = s0 + lane; i < s1; i += 64) {
        int e = eid[i];
        float4 av = *(const float4*)&a1[(size_t)e * 4];
        m[0] = fmaxf(m[0], av.x); m[1] = fmaxf(m[1], av.y);
        m[2] = fmaxf(m[2], av.z); m[3] = fmaxf(m[3], av.w);
    }
#pragma unroll
    for (int d = 1; d < 64; d <<= 1) {
        m[0] = fmaxf(m[0], __shfl_xor(m[0], d, 64));
        m[1] = fmaxf(m[1], __shfl_xor(m[1], d, 64));
        m[2] = fmaxf(m[2], __shfl_xor(m[2], d, 64));
        m[3] = fmaxf(m[3], __shfl_xor(m[3], d, 64));
    }
    if (s1 == s0) {
        hn1o[(size_t)w * 128 + lane] = 0.f;
        hn1o[(size_t)w * 128 + 64 + lane] = 0.f;
        return;
    }
    float den[4] = {0.f, 0.f, 0.f, 0.f};
    for (int i = s0 + lane; i < s1; i += 64) {
        int e = eid[i];
        float4 av = *(const float4*)&a1[(size_t)e * 4];
        den[0] += expf(av.x - m[0]); den[1] += expf(av.y - m[1]);
        den[2] += expf(av.z - m[2]); den[3] += expf(av.w - m[3]);
    }
#pragma unroll
    for (int d = 1; d < 64; d <<= 1) {
        den[0] += __shfl_xor(den[0], d, 64);
        den[1] += __shfl_xor(den[1], d, 64);
        den[2] += __shfl_xor(den[2], d, 64);
        den[3] += __shfl_xor(den[3], d, 64);
    }
    float r[4];
    for (int h = 0; h < 4; ++h) r[h] = 1.f / den[h];
    int h0 = lane >> 5;      // head for output o = lane   (F=32)
    int h1 = h0 + 2;         // head for output o = 64+lane
    float acc0 = 0.f, acc1 = 0.f;
    for (int i = s0; i < s1; ++i) {
        int e = eid[i];
        float4 av = *(const float4*)&a1[(size_t)e * 4];
        float a0 = (h0 == 0) ? av.x : av.y;
        float a1v = (h0 == 0) ? av.z : av.w;
        float w0 = expf(a0 - m[h0]) * r[h0];
        float w1 = expf(a1v - m[h1]) * r[h1];
        int s = src[e];
        const float* hp = &P1[(size_t)s * 384];
        acc0 += w0 * hp[lane];
        acc1 += w1 * hp[64 + lane];
    }
    float e0 = (acc0 > 0.f) ? acc0 : expm1f(acc0);
    float e1 = (acc1 > 0.f) ? acc1 : expm1f(acc1);
    hn1o[(size_t)w * 128 + lane] = e0;
    hn1o[(size_t)w * 128 + 64 + lane] = e1;
}

// ---------------- node projections, layer2: P2[n][0:256]=hp2, [256:512]=pa2, [512:768]=pc2
__global__ __launch_bounds__(256) void k_nodeproj2(
        const float* __restrict__ hn1o, const float* __restrict__ Wn2,
        const float* __restrict__ b2, const float* __restrict__ We2,
        float* __restrict__ P2) {
    __shared__ float Wl[256 * 132];
    __shared__ float Al[32 * 128];
    int tid = threadIdx.x;
    int seg = blockIdx.y;  // 0..2
    for (int t = tid; t < 256 * 32; t += 256) {
        int o = t >> 5, k4 = (t & 31) * 4;
        int og = seg * 256 + o;
        const float* sp;
        if (og < 256)      sp = &Wn2[(size_t)og * 128 + k4];
        else if (og < 512) sp = &We2[(size_t)(og - 256) * 384 + k4];
        else               sp = &We2[(size_t)(og - 512) * 384 + 256 + k4];
        *(float4*)&Wl[o * 132 + k4] = *(const float4*)sp;
    }
    int nb = blockIdx.x * 32;
    for (int t = tid; t < 32 * 32; t += 256) {
        int r = t >> 5, k4 = (t & 31) * 4;
        int n = nb + r;
        float4 v = make_float4(0.f, 0.f, 0.f, 0.f);
        if (n < NN) v = *(const float4*)&hn1o[(size_t)n * 128 + k4];
        *(float4*)&Al[r * 128 + k4] = v;
    }
    __syncthreads();
    int q = tid & 31, rg = tid >> 5;
    float acc[4][8];
    for (int i = 0; i < 4; ++i)
        for (int j = 0; j < 8; ++j) acc[i][j] = 0.f;
    for (int k4 = 0; k4 < 128; k4 += 4) {
        float4 a[4];
#pragma unroll
        for (int i = 0; i < 4; ++i) a[i] = *(float4*)&Al[(rg * 4 + i) * 128 + k4];
#pragma unroll
        for (int j = 0; j < 8; ++j) {
            float4 wv = *(float4*)&Wl[(q + 32 * j) * 132 + k4];
#pragma unroll
            for (int i = 0; i < 4; ++i)
                acc[i][j] += a[i].x * wv.x + a[i].y * wv.y + a[i].z * wv.z + a[i].w * wv.w;
        }
    }
    for (int i = 0; i < 4; ++i) {
        int n = nb + rg * 4 + i;
        if (n >= NN) continue;
        for (int j = 0; j < 8; ++j) {
            int og = seg * 256 + q + 32 * j;
            float v = acc[i][j] + (og < 256 ? b2[og] : 0.f);
            P2[(size_t)n * 768 + og] = v;
        }
    }
}

// ---------------- edge GEMM layer2: a2 + he_out (mean over heads) ----------------
__global__ __launch_bounds__(256) void k_gemm2(
        const float* __restrict__ he1, const int* __restrict__ src,
        const int* __restrict__ dst, const float* __restrict__ We2,
        const float* __restrict__ Wa2, const float* __restrict__ P2,
        float* __restrict__ heo, float* __restrict__ a2) {
    __shared__ float Wl[256 * 132];
    __shared__ float Al[32 * 128];
    __shared__ float aacc[32 * 4];
    int tid = threadIdx.x;
    for (int t = tid; t < 256 * 32; t += 256) {
        int o = t >> 5, k4 = (t & 31) * 4;
        *(float4*)&Wl[o * 132 + k4] = *(const float4*)&We2[(size_t)o * 384 + 128 + k4];
    }
    int eb = blockIdx.x * 32;
    for (int t = tid; t < 32 * 32; t += 256) {
        int r = t >> 5, k4 = (t & 31) * 4;
        *(float4*)&Al[r * 128 + k4] = *(const float4*)&he1[(size_t)(eb + r) * 128 + k4];
    }
    if (tid < 128) aacc[tid] = 0.f;
    __syncthreads();
    int q = tid & 31, rg = tid >> 5;
    float acc[4][8];
    for (int i = 0; i < 4; ++i)
        for (int j = 0; j < 8; ++j) acc[i][j] = 0.f;
    for (int k4 = 0; k4 < 128; k4 += 4) {
        float4 a[4];
#pragma unroll
        for (int i = 0; i < 4; ++i) a[i] = *(float4*)&Al[(rg * 4 + i) * 128 + k4];
#pragma unroll
        for (int j = 0; j < 8; ++j) {
            float4 wv = *(float4*)&Wl[(q + 32 * j) * 132 + k4];
#pragma unroll
            for (int i = 0; i < 4; ++i)
                acc[i][j] += a[i].x * wv.x + a[i].y * wv.y + a[i].z * wv.z + a[i].w * wv.w;
        }
    }
    float was0 = Wa2[q] + Wa2[64 + q] + Wa2[128 + q] + Wa2[192 + q];
    float was1 = Wa2[32 + q] + Wa2[96 + q] + Wa2[160 + q] + Wa2[224 + q];
    for (int i = 0; i < 4; ++i) {
        int e = eb + rg * 4 + i;
        int s = src[e], d = dst[e];
        const float* pa = &P2[(size_t)s * 768 + 256];
        const float* pc = &P2[(size_t)d * 768 + 512];
        float f[8];
        float ap[4] = {0.f, 0.f, 0.f, 0.f};
        for (int j = 0; j < 8; ++j) {
            int o = q + 32 * j;
            float v = acc[i][j] + pa[o] + pc[o];
            v = (v > 0.f) ? v : 0.01f * v;
            f[j] = v;
            ap[j >> 1] += v * ((j & 1) ? was1 : was0);
        }
        float m0 = 0.25f * (f[0] + f[2] + f[4] + f[6]);
        float m1 = 0.25f * (f[1] + f[3] + f[5] + f[7]);
        heo[(size_t)e * 64 + q] = m0;
        heo[(size_t)e * 64 + 32 + q] = m1;
        for (int h = 0; h < 4; ++h)
            atomicAdd(&aacc[(rg * 4 + i) * 4 + h], ap[h]);
    }
    __syncthreads();
    if (tid < 128) {
        int r = tid >> 2, h = tid & 3;
        a2[(size_t)(eb + r) * 4 + h] = aacc[tid];
    }
}

// ---------------- segment softmax + aggregate + head-mean, layer2 ----------------
__global__ void k_agg2(const float* __restrict__ a2, const int* __restrict__ off,
                       const int* __restrict__ eid, const int* __restrict__ src,
                       const float* __restrict__ P2, float* __restrict__ hno) {
    int w = (blockIdx.x * 256 + threadIdx.x) >> 6;
    int lane = threadIdx.x & 63;
    if (w >= NN) return;
    int s0 = off[w], s1 = off[w + 1];
    float m[4] = {-INFINITY, -INFINITY, -INFINITY, -INFINITY};
    for (int i = s0 + lane; i < s1; i += 64) {
        int e = eid[i];
        float4 av = *(const float4*)&a2[(size_t)e * 4];
        m[0] = fmaxf(m[0], av.x); m[1] = fmaxf(m[1], av.y);
        m[2] = fmaxf(m[2], av.z); m[3] = fmaxf(m[3], av.w);
    }
#pragma unroll
    for (int d = 1; d < 64; d <<= 1) {
        m[0] = fmaxf(m[0], __shfl_xor(m[0], d, 64));
        m[1] = fmaxf(m[1], __shfl_xor(m[1], d, 64));
        m[2] = fmaxf(m[2], __shfl_xor(m[2], d, 64));
        m[3] = fmaxf(m[3], __shfl_xor(m[3], d, 64));
    }
    if (s1 == s0) {
        hno[(size_t)w * 64 + lane] = 0.f;
        return;
    }
    float den[4] = {0.f, 0.f, 0.f, 0.f};
    for (int i = s0 + lane; i < s1; i += 64) {
        int e = eid[i];
        float4 av = *(const float4*)&a2[(size_t)e * 4];
        den[0] += expf(av.x - m[0]); den[1] += expf(av.y - m[1]);
        den[2] += expf(av.z - m[2]); den[3] += expf(av.w - m[3]);
    }
#pragma unroll
    for (int d = 1; d < 64; d <<= 1) {
        den[0] += __shfl_xor(den[0], d, 64);
        den[1] += __shfl_xor(den[1], d, 64);
        den[2] += __shfl_xor(den[2], d, 64);
        den[3] += __shfl_xor(den[3], d, 64);
    }
    float r[4];
    for (int h = 0; h < 4; ++h) r[h] = 1.f / den[h];
    float acc0 = 0.f, acc1 = 0.f, acc2 = 0.f, acc3 = 0.f;
    for (int i = s0; i < s1; ++i) {
        int e = eid[i];
        float4 av = *(const float4*)&a2[(size_t)e * 4];
        int s = src[e];
        const float* hp = &P2[(size_t)s * 768];
        acc0 += expf(av.x - m[0]) * r[0] * hp[lane];
        acc1 += expf(av.y - m[1]) * r[1] * hp[64 + lane];
        acc2 += expf(av.z - m[2]) * r[2] * hp[128 + lane];
        acc3 += expf(av.w - m[3]) * r[3] * hp[192 + lane];
    }
    hno[(size_t)w * 64 + lane] = 0.25f * (acc0 + acc1 + acc2 + acc3);
}

extern "C" void kernel_launch(void* const* d_in, const int* in_sizes, int n_in,
                              void* d_out, int out_size, void* d_ws, size_t ws_size,
                              hipStream_t stream) {
    const float* efeats = (const float*)d_in[1];
    const int* src = (const int*)d_in[2];
    const int* dst = (const int*)d_in[3];
    const float* Wn1 = (const float*)d_in[4];
    const float* b1  = (const float*)d_in[5];
    const float* We1 = (const float*)d_in[6];
    const float* Wa1 = (const float*)d_in[7];
    const float* Wn2 = (const float*)d_in[8];
    const float* b2  = (const float*)d_in[9];
    const float* We2 = (const float*)d_in[10];
    const float* Wa2 = (const float*)d_in[11];

    char* ws = (char*)d_ws;
    size_t o = 0;
    auto alloc = [&](size_t bytes) {
        void* p = ws + o;
        o += (bytes + 255) & ~(size_t)255;
        return p;
    };
    int* cnt   = (int*)alloc((size_t)NN * 4);
    int* off   = (int*)alloc((size_t)(NN + 1) * 4);
    int* cur   = (int*)alloc((size_t)NN * 4);
    int* eid   = (int*)alloc((size_t)NE * 4);
    float* hn1 = (float*)alloc((size_t)NN * 64 * 4);
    float* P   = (float*)alloc((size_t)NN * 768 * 4);   // P1 (N x 384) then P2 (N x 768)
    float* he1 = (float*)alloc((size_t)NE * 128 * 4);
    float* a1  = (float*)alloc((size_t)NE * 4 * 4);     // reused as a2
    float* hn1o= (float*)alloc((size_t)NN * 128 * 4);

    float* hno = (float*)d_out;
    float* heo = (float*)d_out + (size_t)NN * 64;

    hipMemsetAsync(cnt, 0, (size_t)NN * 4, stream);
    k_count<<<(NE + 255) / 256, 256, 0, stream>>>(dst, cnt);
    k_scan<<<1, 1024, 0, stream>>>(cnt, off, cur);
    k_fill<<<(NE + 255) / 256, 256, 0, stream>>>(dst, cur, eid);
    k_agg_ef<<<NN / 4, 256, 0, stream>>>(efeats, off, eid, hn1);
    k_nodeproj1<<<(NN + 31) / 32, 256, 0, stream>>>(hn1, Wn1, b1, We1, P);
    k_gemm1<<<NE / 64, 256, 0, stream>>>(efeats, src, dst, We1, Wa1, P, he1, a1);
    k_agg1<<<NN / 4, 256, 0, stream>>>(a1, off, eid, src, P, hn1o);
    dim3 g2((NN + 31) / 32, 3);
    k_nodeproj2<<<g2, 256, 0, stream>>>(hn1o, Wn2, b2, We2, P);
    k_gemm2<<<NE / 32, 256, 0, stream>>>(he1, src, dst, We2, Wa2, P, heo, a1);
    k_agg2<<<NN / 4, 256, 0, stream>>>(a1, off, eid, src, P, hno);
}

// Round 2
// 1178.278 us; speedup vs baseline: 2.2397x; 2.2397x over previous
//
#include <hip/hip_runtime.h>
#include <math.h>

#define NN 30000
#define NE 480000

typedef short bf16x8 __attribute__((ext_vector_type(8)));
typedef float f32x4 __attribute__((ext_vector_type(4)));

static __device__ __forceinline__ unsigned short f2b(float f) {
    union { float f; unsigned u; } v; v.f = f;
    unsigned r = v.u + 0x7FFF + ((v.u >> 16) & 1);
    return (unsigned short)(r >> 16);
}

// ---------------- CSR build (by dst) ----------------
__global__ void k_count(const int* __restrict__ dst, int* __restrict__ cnt) {
    int e = blockIdx.x * 256 + threadIdx.x;
    if (e < NE) atomicAdd(&cnt[dst[e]], 1);
}

__global__ __launch_bounds__(1024) void k_scan(const int* __restrict__ cnt,
                                               int* __restrict__ off,
                                               int* __restrict__ cur) {
    __shared__ int s[1024];
    __shared__ int sbase;
    int tid = threadIdx.x;
    if (tid == 0) sbase = 0;
    __syncthreads();
    for (int start = 0; start < NN; start += 1024) {
        int i = start + tid;
        int v = (i < NN) ? cnt[i] : 0;
        s[tid] = v;
        __syncthreads();
        for (int d = 1; d < 1024; d <<= 1) {
            int t = (tid >= d) ? s[tid - d] : 0;
            __syncthreads();
            s[tid] += t;
            __syncthreads();
        }
        int base = sbase;
        int excl = base + s[tid] - v;
        if (i < NN) { off[i] = excl; cur[i] = excl; }
        __syncthreads();
        if (tid == 0) sbase = base + s[1023];
        __syncthreads();
    }
    if (tid == 0) off[NN] = sbase;
}

__global__ void k_fill(const int* __restrict__ dst, int* __restrict__ cur,
                       int* __restrict__ eid) {
    int e = blockIdx.x * 256 + threadIdx.x;
    if (e < NE) {
        int p = atomicAdd(&cur[dst[e]], 1);
        eid[p] = e;
    }
}

// ---------------- dtype conversions ----------------
__global__ void k_convef(const float* __restrict__ ef, unsigned short* __restrict__ efb) {
    int i = blockIdx.x * 256 + threadIdx.x;   // 8 elems per thread
    if (i >= NE * 64 / 8) return;
    const float4* p = (const float4*)(ef + (size_t)i * 8);
    float4 x = p[0], y = p[1];
    uint4 o;
    o.x = (unsigned)f2b(x.x) | ((unsigned)f2b(x.y) << 16);
    o.y = (unsigned)f2b(x.z) | ((unsigned)f2b(x.w) << 16);
    o.z = (unsigned)f2b(y.x) | ((unsigned)f2b(y.y) << 16);
    o.w = (unsigned)f2b(y.z) | ((unsigned)f2b(y.w) << 16);
    *(uint4*)(efb + (size_t)i * 8) = o;
}

__global__ void k_convw(const float* __restrict__ We1, const float* __restrict__ We2,
                        unsigned short* __restrict__ W1b, unsigned short* __restrict__ W2b) {
    int i = blockIdx.x * 256 + threadIdx.x;
    if (i < 128 * 64) {
        int r = i >> 6, k = i & 63;
        W1b[i] = f2b(We1[(size_t)r * 192 + 64 + k]);
    } else if (i < 128 * 64 + 256 * 128) {
        int j = i - 128 * 64;
        int r = j >> 7, k = j & 127;
        W2b[j] = f2b(We2[(size_t)r * 384 + 128 + k]);
    }
}

// ---------------- layer1: hn1[n] = sum of efeats over in-edges ----------------
__global__ void k_agg_ef(const float* __restrict__ ef, const int* __restrict__ off,
                         const int* __restrict__ eid, float* __restrict__ hn1) {
    int w = (blockIdx.x * 256 + threadIdx.x) >> 6;
    int lane = threadIdx.x & 63;
    if (w >= NN) return;
    int s0 = off[w], s1 = off[w + 1];
    float acc = 0.f;
    for (int i = s0; i < s1; ++i) {
        int e = eid[i];
        acc += ef[(size_t)e * 64 + lane];
    }
    hn1[(size_t)w * 64 + lane] = acc;
}

// ---------------- node projections, layer1: P1[n][0:128]=hp1, [128:256]=pa1, [256:384]=pc1
__global__ __launch_bounds__(256) void k_nodeproj1(
        const float* __restrict__ hn1, const float* __restrict__ Wn1,
        const float* __restrict__ b1, const float* __restrict__ We1,
        float* __restrict__ P1) {
    __shared__ float Wl[384 * 68];
    __shared__ float Al[32 * 64];
    int tid = threadIdx.x;
    for (int t = tid; t < 384 * 16; t += 256) {
        int o = t >> 4, k4 = (t & 15) * 4;
        const float* sp;
        if (o < 128)      sp = &Wn1[o * 64 + k4];
        else if (o < 256) sp = &We1[(size_t)(o - 128) * 192 + k4];
        else              sp = &We1[(size_t)(o - 256) * 192 + 128 + k4];
        *(float4*)&Wl[o * 68 + k4] = *(const float4*)sp;
    }
    int nb = blockIdx.x * 32;
    for (int t = tid; t < 32 * 16; t += 256) {
        int r = t >> 4, k4 = (t & 15) * 4;
        int n = nb + r;
        float4 v = make_float4(0.f, 0.f, 0.f, 0.f);
        if (n < NN) v = *(const float4*)&hn1[(size_t)n * 64 + k4];
        *(float4*)&Al[r * 64 + k4] = v;
    }
    __syncthreads();
    int q = tid & 31, rg = tid >> 5;
    float acc[4][12];
    for (int i = 0; i < 4; ++i)
        for (int j = 0; j < 12; ++j) acc[i][j] = 0.f;
    for (int k4 = 0; k4 < 64; k4 += 4) {
        float4 a[4];
#pragma unroll
        for (int i = 0; i < 4; ++i) a[i] = *(float4*)&Al[(rg * 4 + i) * 64 + k4];
#pragma unroll
        for (int j = 0; j < 12; ++j) {
            float4 wv = *(float4*)&Wl[(q + 32 * j) * 68 + k4];
#pragma unroll
            for (int i = 0; i < 4; ++i)
                acc[i][j] += a[i].x * wv.x + a[i].y * wv.y + a[i].z * wv.z + a[i].w * wv.w;
        }
    }
    for (int i = 0; i < 4; ++i) {
        int n = nb + rg * 4 + i;
        if (n >= NN) continue;
        for (int j = 0; j < 12; ++j) {
            int o = q + 32 * j;
            float v = acc[i][j] + (o < 128 ? b1[o] : 0.f);
            P1[(size_t)n * 384 + o] = v;
        }
    }
}

// ---------------- edge GEMM layer1 (MFMA bf16) ----------------
// f = leaky(efb@W1b.T + pa1[src] + pc1[dst]); a1[e][h]; he1b = bf16(elu-of-leaky)
__global__ __launch_bounds__(256) void k_gemm1(
        const unsigned short* __restrict__ efb, const int* __restrict__ src,
        const int* __restrict__ dst, const unsigned short* __restrict__ W1b,
        const float* __restrict__ Wa1, const float* __restrict__ P1,
        unsigned short* __restrict__ he1b, float* __restrict__ a1) {
    int tid = threadIdx.x;
    int w = tid >> 6, l = tid & 63;
    int c = l & 15, g = l >> 4;
    int eb = blockIdx.x * 64;

    f32x4 acc[4][2];
    for (int m = 0; m < 4; ++m)
        for (int t = 0; t < 2; ++t) acc[m][t] = (f32x4)(0.f);

#pragma unroll
    for (int kk = 0; kk < 2; ++kk) {
        bf16x8 b[2];
#pragma unroll
        for (int t = 0; t < 2; ++t)
            b[t] = *(const bf16x8*)&W1b[(size_t)((2 * w + t) * 16 + c) * 64 + kk * 32 + g * 8];
#pragma unroll
        for (int m = 0; m < 4; ++m) {
            bf16x8 a = *(const bf16x8*)&efb[(size_t)(eb + m * 16 + c) * 64 + kk * 32 + g * 8];
#pragma unroll
            for (int t = 0; t < 2; ++t)
                acc[m][t] = __builtin_amdgcn_mfma_f32_16x16x32_bf16(a, b[t], acc[m][t], 0, 0, 0);
        }
    }

    float wsj[2];
#pragma unroll
    for (int t = 0; t < 2; ++t) {
        int j = t * 16 + c;
        wsj[t] = Wa1[j] + Wa1[32 + j] + Wa1[64 + j] + Wa1[96 + j];
    }

#pragma unroll
    for (int m = 0; m < 4; ++m) {
#pragma unroll
        for (int r = 0; r < 4; ++r) {
            int e = eb + m * 16 + g * 4 + r;
            int s = src[e], d = dst[e];
            const float* pa = &P1[(size_t)s * 384 + 128 + w * 32 + c];
            const float* pc = &P1[(size_t)d * 384 + 256 + w * 32 + c];
            float av = 0.f;
#pragma unroll
            for (int t = 0; t < 2; ++t) {
                float f = acc[m][t][r] + pa[t * 16] + pc[t * 16];
                float lf = (f > 0.f) ? f : 0.01f * f;
                av += lf * wsj[t];
                float el = (lf > 0.f) ? lf : expm1f(lf);
                he1b[(size_t)e * 128 + w * 32 + t * 16 + c] = f2b(el);
            }
            av += __shfl_xor(av, 1, 64);
            av += __shfl_xor(av, 2, 64);
            av += __shfl_xor(av, 4, 64);
            av += __shfl_xor(av, 8, 64);
            if (c == 0) a1[(size_t)e * 4 + w] = av;
        }
    }
}

// ---------------- segment softmax + weighted aggregate, layer1 ----------------
__global__ void k_agg1(const float* __restrict__ a1, const int* __restrict__ off,
                       const int* __restrict__ eid, const int* __restrict__ src,
                       const float* __restrict__ P1, float* __restrict__ hn1o) {
    int w = (blockIdx.x * 256 + threadIdx.x) >> 6;
    int lane = threadIdx.x & 63;
    if (w >= NN) return;
    int s0 = off[w], s1 = off[w + 1];
    float m[4] = {-INFINITY, -INFINITY, -INFINITY, -INFINITY};
    for (int i = s0 + lane; i < s1; i += 64) {
        int e = eid[i];
        float4 av = *(const float4*)&a1[(size_t)e * 4];
        m[0] = fmaxf(m[0], av.x); m[1] = fmaxf(m[1], av.y);
        m[2] = fmaxf(m[2], av.z); m[3] = fmaxf(m[3], av.w);
    }
#pragma unroll
    for (int d = 1; d < 64; d <<= 1) {
        m[0] = fmaxf(m[0], __shfl_xor(m[0], d, 64));
        m[1] = fmaxf(m[1], __shfl_xor(m[1], d, 64));
        m[2] = fmaxf(m[2], __shfl_xor(m[2], d, 64));
        m[3] = fmaxf(m[3], __shfl_xor(m[3], d, 64));
    }
    if (s1 == s0) {
        hn1o[(size_t)w * 128 + lane] = 0.f;
        hn1o[(size_t)w * 128 + 64 + lane] = 0.f;
        return;
    }
    float den[4] = {0.f, 0.f, 0.f, 0.f};
    for (int i = s0 + lane; i < s1; i += 64) {
        int e = eid[i];
        float4 av = *(const float4*)&a1[(size_t)e * 4];
        den[0] += expf(av.x - m[0]); den[1] += expf(av.y - m[1]);
        den[2] += expf(av.z - m[2]); den[3] += expf(av.w - m[3]);
    }
#pragma unroll
    for (int d = 1; d < 64; d <<= 1) {
        den[0] += __shfl_xor(den[0], d, 64);
        den[1] += __shfl_xor(den[1], d, 64);
        den[2] += __shfl_xor(den[2], d, 64);
        den[3] += __shfl_xor(den[3], d, 64);
    }
    float r[4];
    for (int h = 0; h < 4; ++h) r[h] = 1.f / den[h];
    int h0 = lane >> 5;
    int h1 = h0 + 2;
    float acc0 = 0.f, acc1 = 0.f;
    for (int i = s0; i < s1; ++i) {
        int e = eid[i];
        float4 av = *(const float4*)&a1[(size_t)e * 4];
        float a0 = (h0 == 0) ? av.x : av.y;
        float a1v = (h0 == 0) ? av.z : av.w;
        float w0 = expf(a0 - m[h0]) * r[h0];
        float w1 = expf(a1v - m[h1]) * r[h1];
        int s = src[e];
        const float* hp = &P1[(size_t)s * 384];
        acc0 += w0 * hp[lane];
        acc1 += w1 * hp[64 + lane];
    }
    float e0 = (acc0 > 0.f) ? acc0 : expm1f(acc0);
    float e1 = (acc1 > 0.f) ? acc1 : expm1f(acc1);
    hn1o[(size_t)w * 128 + lane] = e0;
    hn1o[(size_t)w * 128 + 64 + lane] = e1;
}

// ---------------- node projections, layer2 ----------------
__global__ __launch_bounds__(256) void k_nodeproj2(
        const float* __restrict__ hn1o, const float* __restrict__ Wn2,
        const float* __restrict__ b2, const float* __restrict__ We2,
        float* __restrict__ P2) {
    __shared__ float Wl[256 * 132];
    __shared__ float Al[32 * 128];
    int tid = threadIdx.x;
    int seg = blockIdx.y;
    for (int t = tid; t < 256 * 32; t += 256) {
        int o = t >> 5, k4 = (t & 31) * 4;
        int og = seg * 256 + o;
        const float* sp;
        if (og < 256)      sp = &Wn2[(size_t)og * 128 + k4];
        else if (og < 512) sp = &We2[(size_t)(og - 256) * 384 + k4];
        else               sp = &We2[(size_t)(og - 512) * 384 + 256 + k4];
        *(float4*)&Wl[o * 132 + k4] = *(const float4*)sp;
    }
    int nb = blockIdx.x * 32;
    for (int t = tid; t < 32 * 32; t += 256) {
        int r = t >> 5, k4 = (t & 31) * 4;
        int n = nb + r;
        float4 v = make_float4(0.f, 0.f, 0.f, 0.f);
        if (n < NN) v = *(const float4*)&hn1o[(size_t)n * 128 + k4];
        *(float4*)&Al[r * 128 + k4] = v;
    }
    __syncthreads();
    int q = tid & 31, rg = tid >> 5;
    float acc[4][8];
    for (int i = 0; i < 4; ++i)
        for (int j = 0; j < 8; ++j) acc[i][j] = 0.f;
    for (int k4 = 0; k4 < 128; k4 += 4) {
        float4 a[4];
#pragma unroll
        for (int i = 0; i < 4; ++i) a[i] = *(float4*)&Al[(rg * 4 + i) * 128 + k4];
#pragma unroll
        for (int j = 0; j < 8; ++j) {
            float4 wv = *(float4*)&Wl[(q + 32 * j) * 132 + k4];
#pragma unroll
            for (int i = 0; i < 4; ++i)
                acc[i][j] += a[i].x * wv.x + a[i].y * wv.y + a[i].z * wv.z + a[i].w * wv.w;
        }
    }
    for (int i = 0; i < 4; ++i) {
        int n = nb + rg * 4 + i;
        if (n >= NN) continue;
        for (int j = 0; j < 8; ++j) {
            int og = seg * 256 + q + 32 * j;
            float v = acc[i][j] + (og < 256 ? b2[og] : 0.f);
            P2[(size_t)n * 768 + og] = v;
        }
    }
}

// ---------------- edge GEMM layer2 (MFMA bf16): a2 + heo ----------------
__global__ __launch_bounds__(256) void k_gemm2(
        const unsigned short* __restrict__ he1b, const int* __restrict__ src,
        const int* __restrict__ dst, const unsigned short* __restrict__ W2b,
        const float* __restrict__ Wa2, const float* __restrict__ P2,
        float* __restrict__ heo, float* __restrict__ a2) {
    __shared__ float a2l[64 * 4];
    int tid = threadIdx.x;
    int w = tid >> 6, l = tid & 63;
    int c = l & 15, g = l >> 4;
    int eb = blockIdx.x * 64;
    a2l[tid] = 0.f;
    __syncthreads();

    f32x4 acc[4][4];
    for (int m = 0; m < 4; ++m)
        for (int t = 0; t < 4; ++t) acc[m][t] = (f32x4)(0.f);

#pragma unroll
    for (int kk = 0; kk < 4; ++kk) {
        bf16x8 b[4];
#pragma unroll
        for (int t = 0; t < 4; ++t)
            b[t] = *(const bf16x8*)&W2b[(size_t)((w + 4 * t) * 16 + c) * 128 + kk * 32 + g * 8];
#pragma unroll
        for (int m = 0; m < 4; ++m) {
            bf16x8 a = *(const bf16x8*)&he1b[(size_t)(eb + m * 16 + c) * 128 + kk * 32 + g * 8];
#pragma unroll
            for (int t = 0; t < 4; ++t)
                acc[m][t] = __builtin_amdgcn_mfma_f32_16x16x32_bf16(a, b[t], acc[m][t], 0, 0, 0);
        }
    }

    int j = w * 16 + c;
    float wsj = Wa2[j] + Wa2[64 + j] + Wa2[128 + j] + Wa2[192 + j];

#pragma unroll
    for (int m = 0; m < 4; ++m) {
#pragma unroll
        for (int r = 0; r < 4; ++r) {
            int le = m * 16 + g * 4 + r;
            int e = eb + le;
            int s = src[e], d = dst[e];
            const float* pa = &P2[(size_t)s * 768 + 256 + j];
            const float* pc = &P2[(size_t)d * 768 + 512 + j];
            float hsum = 0.f;
            float a2v[4];
#pragma unroll
            for (int t = 0; t < 4; ++t) {
                float f = acc[m][t][r] + pa[t * 64] + pc[t * 64];
                float lf = (f > 0.f) ? f : 0.01f * f;
                hsum += lf;
                a2v[t] = lf * wsj;
            }
#pragma unroll
            for (int t = 0; t < 4; ++t) {
                float v = a2v[t];
                v += __shfl_xor(v, 1, 64);
                v += __shfl_xor(v, 2, 64);
                v += __shfl_xor(v, 4, 64);
                v += __shfl_xor(v, 8, 64);
                if (c == 0) atomicAdd(&a2l[le * 4 + t], v);
            }
            heo[(size_t)e * 64 + j] = 0.25f * hsum;
        }
    }
    __syncthreads();
    {
        int e = eb + (tid >> 2);
        a2[(size_t)e * 4 + (tid & 3)] = a2l[tid];
    }
}

// ---------------- segment softmax + aggregate + head-mean, layer2 ----------------
__global__ void k_agg2(const float* __restrict__ a2, const int* __restrict__ off,
                       const int* __restrict__ eid, const int* __restrict__ src,
                       const float* __restrict__ P2, float* __restrict__ hno) {
    int w = (blockIdx.x * 256 + threadIdx.x) >> 6;
    int lane = threadIdx.x & 63;
    if (w >= NN) return;
    int s0 = off[w], s1 = off[w + 1];
    float m[4] = {-INFINITY, -INFINITY, -INFINITY, -INFINITY};
    for (int i = s0 + lane; i < s1; i += 64) {
        int e = eid[i];
        float4 av = *(const float4*)&a2[(size_t)e * 4];
        m[0] = fmaxf(m[0], av.x); m[1] = fmaxf(m[1], av.y);
        m[2] = fmaxf(m[2], av.z); m[3] = fmaxf(m[3], av.w);
    }
#pragma unroll
    for (int d = 1; d < 64; d <<= 1) {
        m[0] = fmaxf(m[0], __shfl_xor(m[0], d, 64));
        m[1] = fmaxf(m[1], __shfl_xor(m[1], d, 64));
        m[2] = fmaxf(m[2], __shfl_xor(m[2], d, 64));
        m[3] = fmaxf(m[3], __shfl_xor(m[3], d, 64));
    }
    if (s1 == s0) {
        hno[(size_t)w * 64 + lane] = 0.f;
        return;
    }
    float den[4] = {0.f, 0.f, 0.f, 0.f};
    for (int i = s0 + lane; i < s1; i += 64) {
        int e = eid[i];
        float4 av = *(const float4*)&a2[(size_t)e * 4];
        den[0] += expf(av.x - m[0]); den[1] += expf(av.y - m[1]);
        den[2] += expf(av.z - m[2]); den[3] += expf(av.w - m[3]);
    }
#pragma unroll
    for (int d = 1; d < 64; d <<= 1) {
        den[0] += __shfl_xor(den[0], d, 64);
        den[1] += __shfl_xor(den[1], d, 64);
        den[2] += __shfl_xor(den[2], d, 64);
        den[3] += __shfl_xor(den[3], d, 64);
    }
    float r[4];
    for (int h = 0; h < 4; ++h) r[h] = 1.f / den[h];
    float acc0 = 0.f, acc1 = 0.f, acc2 = 0.f, acc3 = 0.f;
    for (int i = s0; i < s1; ++i) {
        int e = eid[i];
        float4 av = *(const float4*)&a2[(size_t)e * 4];
        int s = src[e];
        const float* hp = &P2[(size_t)s * 768];
        acc0 += expf(av.x - m[0]) * r[0] * hp[lane];
        acc1 += expf(av.y - m[1]) * r[1] * hp[64 + lane];
        acc2 += expf(av.z - m[2]) * r[2] * hp[128 + lane];
        acc3 += expf(av.w - m[3]) * r[3] * hp[192 + lane];
    }
    hno[(size_t)w * 64 + lane] = 0.25f * (acc0 + acc1 + acc2 + acc3);
}

extern "C" void kernel_launch(void* const* d_in, const int* in_sizes, int n_in,
                              void* d_out, int out_size, void* d_ws, size_t ws_size,
                              hipStream_t stream) {
    const float* efeats = (const float*)d_in[1];
    const int* src = (const int*)d_in[2];
    const int* dst = (const int*)d_in[3];
    const float* Wn1 = (const float*)d_in[4];
    const float* b1  = (const float*)d_in[5];
    const float* We1 = (const float*)d_in[6];
    const float* Wa1 = (const float*)d_in[7];
    const float* Wn2 = (const float*)d_in[8];
    const float* b2  = (const float*)d_in[9];
    const float* We2 = (const float*)d_in[10];
    const float* Wa2 = (const float*)d_in[11];

    char* ws = (char*)d_ws;
    size_t o = 0;
    auto alloc = [&](size_t bytes) {
        void* p = ws + o;
        o += (bytes + 255) & ~(size_t)255;
        return p;
    };
    int* cnt   = (int*)alloc((size_t)NN * 4);
    int* off   = (int*)alloc((size_t)(NN + 1) * 4);
    int* cur   = (int*)alloc((size_t)NN * 4);
    int* eid   = (int*)alloc((size_t)NE * 4);
    float* hn1 = (float*)alloc((size_t)NN * 64 * 4);
    float* P   = (float*)alloc((size_t)NN * 768 * 4);
    unsigned short* he1b = (unsigned short*)alloc((size_t)NE * 128 * 2);
    unsigned short* efb  = (unsigned short*)alloc((size_t)NE * 64 * 2);
    unsigned short* W1b  = (unsigned short*)alloc((size_t)128 * 64 * 2);
    unsigned short* W2b  = (unsigned short*)alloc((size_t)256 * 128 * 2);
    float* a1  = (float*)alloc((size_t)NE * 4 * 4);
    float* hn1o= (float*)alloc((size_t)NN * 128 * 4);

    float* hno = (float*)d_out;
    float* heo = (float*)d_out + (size_t)NN * 64;

    hipMemsetAsync(cnt, 0, (size_t)NN * 4, stream);
    k_count<<<(NE + 255) / 256, 256, 0, stream>>>(dst, cnt);
    k_convef<<<(NE * 64 / 8 + 255) / 256, 256, 0, stream>>>(efeats, efb);
    k_convw<<<(128 * 64 + 256 * 128 + 255) / 256, 256, 0, stream>>>(We1, We2, W1b, W2b);
    k_scan<<<1, 1024, 0, stream>>>(cnt, off, cur);
    k_fill<<<(NE + 255) / 256, 256, 0, stream>>>(dst, cur, eid);
    k_agg_ef<<<NN / 4, 256, 0, stream>>>(efeats, off, eid, hn1);
    k_nodeproj1<<<(NN + 31) / 32, 256, 0, stream>>>(hn1, Wn1, b1, We1, P);
    k_gemm1<<<NE / 64, 256, 0, stream>>>(efb, src, dst, W1b, Wa1, P, he1b, a1);
    k_agg1<<<NN / 4, 256, 0, stream>>>(a1, off, eid, src, P, hn1o);
    dim3 g2((NN + 31) / 32, 3);
    k_nodeproj2<<<g2, 256, 0, stream>>>(hn1o, Wn2, b2, We2, P);
    k_gemm2<<<NE / 64, 256, 0, stream>>>(he1b, src, dst, W2b, Wa2, P, heo, a1);
    k_agg2<<<NN / 4, 256, 0, stream>>>(a1, off, eid, src, P, hno);
}

// Round 4
// 1060.564 us; speedup vs baseline: 2.4883x; 1.1110x over previous
//
#include <hip/hip_runtime.h>
#include <math.h>

#define NN 30000
#define NE 480000

typedef short bf16x8 __attribute__((ext_vector_type(8)));
typedef float f32x4 __attribute__((ext_vector_type(4)));

static __device__ __forceinline__ unsigned short f2b(float f) {
    union { float f; unsigned u; } v; v.f = f;
    unsigned r = v.u + 0x7FFF + ((v.u >> 16) & 1);
    return (unsigned short)(r >> 16);
}
static __device__ __forceinline__ float blo(unsigned u) {
    union { unsigned x; float f; } v; v.x = u << 16; return v.f;
}
static __device__ __forceinline__ float bhi(unsigned u) {
    union { unsigned x; float f; } v; v.x = u & 0xffff0000u; return v.f;
}

// ---------------- CSR build (by dst) ----------------
__global__ void k_count(const int* __restrict__ dst, int* __restrict__ cnt) {
    int e = blockIdx.x * 256 + threadIdx.x;
    if (e < NE) atomicAdd(&cnt[dst[e]], 1);
}

__global__ __launch_bounds__(1024) void k_scanA(const int* __restrict__ cnt,
                                                int* __restrict__ off,
                                                int* __restrict__ bsum) {
    __shared__ int s[1024];
    int tid = threadIdx.x;
    int i = blockIdx.x * 1024 + tid;
    int v = (i < NN) ? cnt[i] : 0;
    s[tid] = v;
    __syncthreads();
    for (int d = 1; d < 1024; d <<= 1) {
        int t = (tid >= d) ? s[tid - d] : 0;
        __syncthreads();
        s[tid] += t;
        __syncthreads();
    }
    if (i < NN) off[i] = s[tid] - v;
    if (tid == 1023) bsum[blockIdx.x] = s[1023];
}

__global__ void k_scanB(const int* __restrict__ bsum, int* __restrict__ bbase, int nb) {
    if (threadIdx.x == 0) {
        int run = 0;
        for (int i = 0; i < nb; ++i) { bbase[i] = run; run += bsum[i]; }
    }
}

__global__ __launch_bounds__(1024) void k_scanC(int* __restrict__ off,
                                                int* __restrict__ cur,
                                                const int* __restrict__ bbase) {
    int i = blockIdx.x * 1024 + threadIdx.x;
    if (i < NN) {
        int o = off[i] + bbase[blockIdx.x];
        off[i] = o;
        cur[i] = o;
        if (i == 0) off[NN] = NE;
    }
}

__global__ void k_fill(const int* __restrict__ dst, int* __restrict__ cur,
                       int* __restrict__ eid) {
    int e = blockIdx.x * 256 + threadIdx.x;
    if (e < NE) {
        int p = atomicAdd(&cur[dst[e]], 1);
        eid[p] = e;
    }
}

// ---------------- permute edges into CSR order + convert ef to bf16 ----------------
__global__ void k_perm(const float* __restrict__ ef, const int* __restrict__ eid,
                       const int* __restrict__ src, const int* __restrict__ dst,
                       unsigned short* __restrict__ efb_p, int* __restrict__ src_p,
                       int* __restrict__ dst_p) {
    int gid = blockIdx.x * 256 + threadIdx.x;
    if (gid >= NE * 8) return;
    int i = gid >> 3, sub = gid & 7;
    int e = eid[i];
    if (sub == 0) { src_p[i] = src[e]; dst_p[i] = dst[e]; }
    const float4* p = (const float4*)(ef + (size_t)e * 64 + sub * 8);
    float4 x = p[0], y = p[1];
    uint4 o;
    o.x = (unsigned)f2b(x.x) | ((unsigned)f2b(x.y) << 16);
    o.y = (unsigned)f2b(x.z) | ((unsigned)f2b(x.w) << 16);
    o.z = (unsigned)f2b(y.x) | ((unsigned)f2b(y.y) << 16);
    o.w = (unsigned)f2b(y.z) | ((unsigned)f2b(y.w) << 16);
    *(uint4*)(efb_p + (size_t)i * 64 + sub * 8) = o;
}

__global__ void k_convw(const float* __restrict__ We1, const float* __restrict__ We2,
                        unsigned short* __restrict__ W1b, unsigned short* __restrict__ W2b) {
    int i = blockIdx.x * 256 + threadIdx.x;
    if (i < 128 * 64) {
        int r = i >> 6, k = i & 63;
        W1b[i] = f2b(We1[(size_t)r * 192 + 64 + k]);
    } else if (i < 128 * 64 + 256 * 128) {
        int j = i - 128 * 64;
        int r = j >> 7, k = j & 127;
        W2b[j] = f2b(We2[(size_t)r * 384 + 128 + k]);
    }
}

// ---------------- layer1: hn1[n] = sum of in-edge feats (streamed, CSR order) ----------------
__global__ void k_agg_ef(const unsigned short* __restrict__ efb_p,
                         const int* __restrict__ off, float* __restrict__ hn1) {
    int w = (blockIdx.x * 256 + threadIdx.x) >> 6;
    int lane = threadIdx.x & 63;
    if (w >= NN) return;
    int s0 = off[w], s1 = off[w + 1];
    int half = lane >> 5, q = lane & 31;
    float a0 = 0.f, a1 = 0.f;
    const unsigned* efu = (const unsigned*)efb_p;
    for (int i = s0 + half; i < s1; i += 2) {
        unsigned u = efu[(size_t)i * 32 + q];
        a0 += blo(u); a1 += bhi(u);
    }
    a0 += __shfl_xor(a0, 32, 64);
    a1 += __shfl_xor(a1, 32, 64);
    if (half == 0) {
        float2 v = make_float2(a0, a1);
        *(float2*)&hn1[(size_t)w * 64 + 2 * q] = v;
    }
}

// ---------------- node projections, layer1 -> fp32 tables hp1/pa1/pc1 (interleaved) ----------------
static __device__ __forceinline__ void store_p1(float* hp1, float* pa1,
                                                float* pc1, int n, int o, float v) {
    if (o < 128) {
        hp1[(size_t)n * 128 + (o & 63) * 2 + (o >> 6)] = v;
    } else if (o < 256) {
        int x = o - 128;
        pa1[(size_t)n * 128 + ((x >> 5) * 16 + (x & 15)) * 2 + ((x >> 4) & 1)] = v;
    } else {
        int x = o - 256;
        pc1[(size_t)n * 128 + ((x >> 5) * 16 + (x & 15)) * 2 + ((x >> 4) & 1)] = v;
    }
}

__global__ __launch_bounds__(256) void k_nodeproj1(
        const float* __restrict__ hn1, const float* __restrict__ Wn1,
        const float* __restrict__ b1, const float* __restrict__ We1,
        float* __restrict__ hp1, float* __restrict__ pa1,
        float* __restrict__ pc1) {
    __shared__ float Wl[384 * 68];
    __shared__ float Al[32 * 64];
    int tid = threadIdx.x;
    for (int t = tid; t < 384 * 16; t += 256) {
        int o = t >> 4, k4 = (t & 15) * 4;
        const float* sp;
        if (o < 128)      sp = &Wn1[o * 64 + k4];
        else if (o < 256) sp = &We1[(size_t)(o - 128) * 192 + k4];
        else              sp = &We1[(size_t)(o - 256) * 192 + 128 + k4];
        *(float4*)&Wl[o * 68 + k4] = *(const float4*)sp;
    }
    int nb = blockIdx.x * 32;
    for (int t = tid; t < 32 * 16; t += 256) {
        int r = t >> 4, k4 = (t & 15) * 4;
        int n = nb + r;
        float4 v = make_float4(0.f, 0.f, 0.f, 0.f);
        if (n < NN) v = *(const float4*)&hn1[(size_t)n * 64 + k4];
        *(float4*)&Al[r * 64 + k4] = v;
    }
    __syncthreads();
    int q = tid & 31, rg = tid >> 5;
    float acc[4][12];
    for (int i = 0; i < 4; ++i)
        for (int j = 0; j < 12; ++j) acc[i][j] = 0.f;
    for (int k4 = 0; k4 < 64; k4 += 4) {
        float4 a[4];
#pragma unroll
        for (int i = 0; i < 4; ++i) a[i] = *(float4*)&Al[(rg * 4 + i) * 64 + k4];
#pragma unroll
        for (int j = 0; j < 12; ++j) {
            float4 wv = *(float4*)&Wl[(q + 32 * j) * 68 + k4];
#pragma unroll
            for (int i = 0; i < 4; ++i)
                acc[i][j] += a[i].x * wv.x + a[i].y * wv.y + a[i].z * wv.z + a[i].w * wv.w;
        }
    }
    for (int i = 0; i < 4; ++i) {
        int n = nb + rg * 4 + i;
        if (n >= NN) continue;
        for (int j = 0; j < 12; ++j) {
            int o = q + 32 * j;
            float v = acc[i][j] + (o < 128 ? b1[o] : 0.f);
            store_p1(hp1, pa1, pc1, n, o, v);
        }
    }
}

// ---------------- edge GEMM layer1 (MFMA bf16, CSR order) ----------------
__global__ __launch_bounds__(256) void k_gemm1(
        const unsigned short* __restrict__ efb_p, const int* __restrict__ src_p,
        const int* __restrict__ dst_p, const unsigned short* __restrict__ W1b,
        const float* __restrict__ Wa1, const float* __restrict__ pa1,
        const float* __restrict__ pc1,
        unsigned short* __restrict__ he1b, float* __restrict__ a1) {
    int tid = threadIdx.x;
    int w = tid >> 6, l = tid & 63;
    int c = l & 15, g = l >> 4;
    int pb = blockIdx.x * 64;

    f32x4 acc[4][2];
    for (int m = 0; m < 4; ++m)
        for (int t = 0; t < 2; ++t) acc[m][t] = (f32x4)(0.f);

#pragma unroll
    for (int kk = 0; kk < 2; ++kk) {
        bf16x8 b[2];
#pragma unroll
        for (int t = 0; t < 2; ++t)
            b[t] = *(const bf16x8*)&W1b[(size_t)((2 * w + t) * 16 + c) * 64 + kk * 32 + g * 8];
#pragma unroll
        for (int m = 0; m < 4; ++m) {
            bf16x8 a = *(const bf16x8*)&efb_p[(size_t)(pb + m * 16 + c) * 64 + kk * 32 + g * 8];
#pragma unroll
            for (int t = 0; t < 2; ++t)
                acc[m][t] = __builtin_amdgcn_mfma_f32_16x16x32_bf16(a, b[t], acc[m][t], 0, 0, 0);
        }
    }

    float wsj0 = Wa1[c] + Wa1[32 + c] + Wa1[64 + c] + Wa1[96 + c];
    float wsj1 = Wa1[16 + c] + Wa1[48 + c] + Wa1[80 + c] + Wa1[112 + c];
    const float2* paF = (const float2*)pa1;
    const float2* pcF = (const float2*)pc1;

#pragma unroll
    for (int m = 0; m < 4; ++m) {
#pragma unroll
        for (int r = 0; r < 4; ++r) {
            int pos = pb + m * 16 + g * 4 + r;
            int s = src_p[pos], d = dst_p[pos];
            float2 ua = paF[(size_t)s * 64 + w * 16 + c];
            float2 uc = pcF[(size_t)d * 64 + w * 16 + c];
            float f0 = acc[m][0][r] + ua.x + uc.x;
            float f1 = acc[m][1][r] + ua.y + uc.y;
            float lf0 = (f0 > 0.f) ? f0 : 0.01f * f0;
            float lf1 = (f1 > 0.f) ? f1 : 0.01f * f1;
            float av = lf0 * wsj0 + lf1 * wsj1;
            he1b[(size_t)pos * 128 + w * 32 + c]      = f2b((lf0 > 0.f) ? lf0 : expm1f(lf0));
            he1b[(size_t)pos * 128 + w * 32 + 16 + c] = f2b((lf1 > 0.f) ? lf1 : expm1f(lf1));
            av += __shfl_xor(av, 1, 64);
            av += __shfl_xor(av, 2, 64);
            av += __shfl_xor(av, 4, 64);
            av += __shfl_xor(av, 8, 64);
            if (c == 0) a1[(size_t)pos * 4 + w] = av;
        }
    }
}

// ---------------- segment softmax + weighted aggregate, layer1 ----------------
__global__ void k_agg1(const float* __restrict__ a1, const int* __restrict__ off,
                       const int* __restrict__ src_p, const float* __restrict__ hp1,
                       float* __restrict__ hn1o) {
    int w = (blockIdx.x * 256 + threadIdx.x) >> 6;
    int lane = threadIdx.x & 63;
    if (w >= NN) return;
    int s0 = off[w], s1 = off[w + 1];
    if (s1 == s0) {
        hn1o[(size_t)w * 128 + lane] = 0.f;
        hn1o[(size_t)w * 128 + 64 + lane] = 0.f;
        return;
    }
    float m[4] = {-INFINITY, -INFINITY, -INFINITY, -INFINITY};
    for (int i = s0 + lane; i < s1; i += 64) {
        float4 av = *(const float4*)&a1[(size_t)i * 4];
        m[0] = fmaxf(m[0], av.x); m[1] = fmaxf(m[1], av.y);
        m[2] = fmaxf(m[2], av.z); m[3] = fmaxf(m[3], av.w);
    }
#pragma unroll
    for (int d = 1; d < 64; d <<= 1) {
        m[0] = fmaxf(m[0], __shfl_xor(m[0], d, 64));
        m[1] = fmaxf(m[1], __shfl_xor(m[1], d, 64));
        m[2] = fmaxf(m[2], __shfl_xor(m[2], d, 64));
        m[3] = fmaxf(m[3], __shfl_xor(m[3], d, 64));
    }
    float den[4] = {0.f, 0.f, 0.f, 0.f};
    for (int i = s0 + lane; i < s1; i += 64) {
        float4 av = *(const float4*)&a1[(size_t)i * 4];
        den[0] += expf(av.x - m[0]); den[1] += expf(av.y - m[1]);
        den[2] += expf(av.z - m[2]); den[3] += expf(av.w - m[3]);
    }
#pragma unroll
    for (int d = 1; d < 64; d <<= 1) {
        den[0] += __shfl_xor(den[0], d, 64);
        den[1] += __shfl_xor(den[1], d, 64);
        den[2] += __shfl_xor(den[2], d, 64);
        den[3] += __shfl_xor(den[3], d, 64);
    }
    int h0 = lane >> 5, h1 = h0 + 2;
    float r0 = 1.f / den[h0], r1 = 1.f / den[h1];
    float m0 = m[h0], m1 = m[h1];
    const float2* hpF = (const float2*)hp1;
    float acc0 = 0.f, acc1 = 0.f;
    for (int i = s0; i < s1; ++i) {
        float4 av = *(const float4*)&a1[(size_t)i * 4];
        float a0 = (h0 == 0) ? av.x : av.y;
        float a1v = (h0 == 0) ? av.z : av.w;
        float w0 = expf(a0 - m0) * r0;
        float w1 = expf(a1v - m1) * r1;
        int s = src_p[i];
        float2 u = hpF[(size_t)s * 64 + lane];
        acc0 += w0 * u.x;
        acc1 += w1 * u.y;
    }
    float e0 = (acc0 > 0.f) ? acc0 : expm1f(acc0);
    float e1 = (acc1 > 0.f) ? acc1 : expm1f(acc1);
    hn1o[(size_t)w * 128 + lane] = e0;
    hn1o[(size_t)w * 128 + 64 + lane] = e1;
}

// ---------------- node projections, layer2 -> fp32 tables hp2/pa2/pc2 (interleaved) ----------------
static __device__ __forceinline__ void store_p2(float* hp2, float* pa2,
                                                float* pc2, int n, int o, float v) {
    if (o < 256) {
        hp2[(size_t)n * 256 + (o & 63) * 4 + (o >> 6)] = v;
    } else if (o < 512) {
        int x = o - 256;
        pa2[(size_t)n * 256 + (x & 63) * 4 + (x >> 6)] = v;
    } else {
        int x = o - 512;
        pc2[(size_t)n * 256 + (x & 63) * 4 + (x >> 6)] = v;
    }
}

__global__ __launch_bounds__(256) void k_nodeproj2(
        const float* __restrict__ hn1o, const float* __restrict__ Wn2,
        const float* __restrict__ b2, const float* __restrict__ We2,
        float* __restrict__ hp2, float* __restrict__ pa2,
        float* __restrict__ pc2) {
    __shared__ float Wl[256 * 132];
    __shared__ float Al[32 * 128];
    int tid = threadIdx.x;
    int seg = blockIdx.y;
    for (int t = tid; t < 256 * 32; t += 256) {
        int o = t >> 5, k4 = (t & 31) * 4;
        int og = seg * 256 + o;
        const float* sp;
        if (og < 256)      sp = &Wn2[(size_t)og * 128 + k4];
        else if (og < 512) sp = &We2[(size_t)(og - 256) * 384 + k4];
        else               sp = &We2[(size_t)(og - 512) * 384 + 256 + k4];
        *(float4*)&Wl[o * 132 + k4] = *(const float4*)sp;
    }
    int nb = blockIdx.x * 32;
    for (int t = tid; t < 32 * 32; t += 256) {
        int r = t >> 5, k4 = (t & 31) * 4;
        int n = nb + r;
        float4 v = make_float4(0.f, 0.f, 0.f, 0.f);
        if (n < NN) v = *(const float4*)&hn1o[(size_t)n * 128 + k4];
        *(float4*)&Al[r * 128 + k4] = v;
    }
    __syncthreads();
    int q = tid & 31, rg = tid >> 5;
    float acc[4][8];
    for (int i = 0; i < 4; ++i)
        for (int j = 0; j < 8; ++j) acc[i][j] = 0.f;
    for (int k4 = 0; k4 < 128; k4 += 4) {
        float4 a[4];
#pragma unroll
        for (int i = 0; i < 4; ++i) a[i] = *(float4*)&Al[(rg * 4 + i) * 128 + k4];
#pragma unroll
        for (int j = 0; j < 8; ++j) {
            float4 wv = *(float4*)&Wl[(q + 32 * j) * 132 + k4];
#pragma unroll
            for (int i = 0; i < 4; ++i)
                acc[i][j] += a[i].x * wv.x + a[i].y * wv.y + a[i].z * wv.z + a[i].w * wv.w;
        }
    }
    for (int i = 0; i < 4; ++i) {
        int n = nb + rg * 4 + i;
        if (n >= NN) continue;
        for (int j = 0; j < 8; ++j) {
            int og = seg * 256 + q + 32 * j;
            float v = acc[i][j] + (og < 256 ? b2[og] : 0.f);
            store_p2(hp2, pa2, pc2, n, og, v);
        }
    }
}

// ---------------- edge GEMM layer2 (MFMA bf16, CSR order): a2 + heo ----------------
__global__ __launch_bounds__(256) void k_gemm2(
        const unsigned short* __restrict__ he1b, const int* __restrict__ src_p,
        const int* __restrict__ dst_p, const int* __restrict__ eid,
        const unsigned short* __restrict__ W2b, const float* __restrict__ Wa2,
        const float* __restrict__ pa2, const float* __restrict__ pc2,
        float* __restrict__ heo, float* __restrict__ a2) {
    __shared__ float a2l[64 * 4];
    int tid = threadIdx.x;
    int w = tid >> 6, l = tid & 63;
    int c = l & 15, g = l >> 4;
    int j = w * 16 + c;
    int pb = blockIdx.x * 64;
    a2l[tid] = 0.f;
    __syncthreads();

    f32x4 acc[4][4];
    for (int m = 0; m < 4; ++m)
        for (int t = 0; t < 4; ++t) acc[m][t] = (f32x4)(0.f);

#pragma unroll
    for (int kk = 0; kk < 4; ++kk) {
        bf16x8 b[4];
#pragma unroll
        for (int t = 0; t < 4; ++t)
            b[t] = *(const bf16x8*)&W2b[(size_t)((w + 4 * t) * 16 + c) * 128 + kk * 32 + g * 8];
#pragma unroll
        for (int m = 0; m < 4; ++m) {
            bf16x8 a = *(const bf16x8*)&he1b[(size_t)(pb + m * 16 + c) * 128 + kk * 32 + g * 8];
#pragma unroll
            for (int t = 0; t < 4; ++t)
                acc[m][t] = __builtin_amdgcn_mfma_f32_16x16x32_bf16(a, b[t], acc[m][t], 0, 0, 0);
        }
    }

    float wsj = Wa2[j] + Wa2[64 + j] + Wa2[128 + j] + Wa2[192 + j];
    const float4* paF = (const float4*)pa2;
    const float4* pcF = (const float4*)pc2;

#pragma unroll
    for (int m = 0; m < 4; ++m) {
#pragma unroll
        for (int r = 0; r < 4; ++r) {
            int le = m * 16 + g * 4 + r;
            int pos = pb + le;
            int s = src_p[pos], d = dst_p[pos];
            int e = eid[pos];
            float4 ua = paF[(size_t)s * 64 + j];
            float4 uc = pcF[(size_t)d * 64 + j];
            float f[4];
            f[0] = acc[m][0][r] + ua.x + uc.x;
            f[1] = acc[m][1][r] + ua.y + uc.y;
            f[2] = acc[m][2][r] + ua.z + uc.z;
            f[3] = acc[m][3][r] + ua.w + uc.w;
            float hsum = 0.f;
#pragma unroll
            for (int t = 0; t < 4; ++t) {
                float lf = (f[t] > 0.f) ? f[t] : 0.01f * f[t];
                f[t] = lf;
                hsum += lf;
            }
#pragma unroll
            for (int t = 0; t < 4; ++t) {
                float v = f[t] * wsj;
                v += __shfl_xor(v, 1, 64);
                v += __shfl_xor(v, 2, 64);
                v += __shfl_xor(v, 4, 64);
                v += __shfl_xor(v, 8, 64);
                if (c == 0) atomicAdd(&a2l[le * 4 + t], v);
            }
            heo[(size_t)e * 64 + j] = 0.25f * hsum;
        }
    }
    __syncthreads();
    {
        int pos = pb + (tid >> 2);
        a2[(size_t)pos * 4 + (tid & 3)] = a2l[tid];
    }
}

// ---------------- segment softmax + aggregate + head-mean, layer2 ----------------
__global__ void k_agg2(const float* __restrict__ a2, const int* __restrict__ off,
                       const int* __restrict__ src_p, const float* __restrict__ hp2,
                       float* __restrict__ hno) {
    int w = (blockIdx.x * 256 + threadIdx.x) >> 6;
    int lane = threadIdx.x & 63;
    if (w >= NN) return;
    int s0 = off[w], s1 = off[w + 1];
    if (s1 == s0) {
        hno[(size_t)w * 64 + lane] = 0.f;
        return;
    }
    float m[4] = {-INFINITY, -INFINITY, -INFINITY, -INFINITY};
    for (int i = s0 + lane; i < s1; i += 64) {
        float4 av = *(const float4*)&a2[(size_t)i * 4];
        m[0] = fmaxf(m[0], av.x); m[1] = fmaxf(m[1], av.y);
        m[2] = fmaxf(m[2], av.z); m[3] = fmaxf(m[3], av.w);
    }
#pragma unroll
    for (int d = 1; d < 64; d <<= 1) {
        m[0] = fmaxf(m[0], __shfl_xor(m[0], d, 64));
        m[1] = fmaxf(m[1], __shfl_xor(m[1], d, 64));
        m[2] = fmaxf(m[2], __shfl_xor(m[2], d, 64));
        m[3] = fmaxf(m[3], __shfl_xor(m[3], d, 64));
    }
    float den[4] = {0.f, 0.f, 0.f, 0.f};
    for (int i = s0 + lane; i < s1; i += 64) {
        float4 av = *(const float4*)&a2[(size_t)i * 4];
        den[0] += expf(av.x - m[0]); den[1] += expf(av.y - m[1]);
        den[2] += expf(av.z - m[2]); den[3] += expf(av.w - m[3]);
    }
#pragma unroll
    for (int d = 1; d < 64; d <<= 1) {
        den[0] += __shfl_xor(den[0], d, 64);
        den[1] += __shfl_xor(den[1], d, 64);
        den[2] += __shfl_xor(den[2], d, 64);
        den[3] += __shfl_xor(den[3], d, 64);
    }
    float r0 = 1.f / den[0], r1 = 1.f / den[1], r2 = 1.f / den[2], r3 = 1.f / den[3];
    const float4* hpF = (const float4*)hp2;
    float acc0 = 0.f, acc1 = 0.f, acc2 = 0.f, acc3 = 0.f;
    for (int i = s0; i < s1; ++i) {
        float4 av = *(const float4*)&a2[(size_t)i * 4];
        int s = src_p[i];
        float4 u = hpF[(size_t)s * 64 + lane];
        acc0 += expf(av.x - m[0]) * r0 * u.x;
        acc1 += expf(av.y - m[1]) * r1 * u.y;
        acc2 += expf(av.z - m[2]) * r2 * u.z;
        acc3 += expf(av.w - m[3]) * r3 * u.w;
    }
    hno[(size_t)w * 64 + lane] = 0.25f * (acc0 + acc1 + acc2 + acc3);
}

extern "C" void kernel_launch(void* const* d_in, const int* in_sizes, int n_in,
                              void* d_out, int out_size, void* d_ws, size_t ws_size,
                              hipStream_t stream) {
    const float* efeats = (const float*)d_in[1];
    const int* src = (const int*)d_in[2];
    const int* dst = (const int*)d_in[3];
    const float* Wn1 = (const float*)d_in[4];
    const float* b1  = (const float*)d_in[5];
    const float* We1 = (const float*)d_in[6];
    const float* Wa1 = (const float*)d_in[7];
    const float* Wn2 = (const float*)d_in[8];
    const float* b2  = (const float*)d_in[9];
    const float* We2 = (const float*)d_in[10];
    const float* Wa2 = (const float*)d_in[11];

    char* ws = (char*)d_ws;
    size_t o = 0;
    auto alloc = [&](size_t bytes) {
        void* p = ws + o;
        o += (bytes + 255) & ~(size_t)255;
        return p;
    };
    int* cnt   = (int*)alloc((size_t)NN * 4);
    int* off   = (int*)alloc((size_t)(NN + 1) * 4);
    int* cur   = (int*)alloc((size_t)NN * 4);
    int* eid   = (int*)alloc((size_t)NE * 4);
    int* src_p = (int*)alloc((size_t)NE * 4);
    int* dst_p = (int*)alloc((size_t)NE * 4);
    int* bsum  = (int*)alloc(64 * 4);
    int* bbase = (int*)alloc(64 * 4);
    float* hn1 = (float*)alloc((size_t)NN * 64 * 4);
    float* hn1o= (float*)alloc((size_t)NN * 128 * 4);
    float* a1  = (float*)alloc((size_t)NE * 4 * 4);   // reused as a2
    unsigned short* efb_p = (unsigned short*)alloc((size_t)NE * 64 * 2);
    unsigned short* he1b  = (unsigned short*)alloc((size_t)NE * 128 * 2);
    unsigned short* W1b   = (unsigned short*)alloc((size_t)128 * 64 * 2);
    unsigned short* W2b   = (unsigned short*)alloc((size_t)256 * 128 * 2);
    float* hp1   = (float*)alloc((size_t)NN * 128 * 4);
    float* pa1   = (float*)alloc((size_t)NN * 128 * 4);
    float* pc1   = (float*)alloc((size_t)NN * 128 * 4);
    float* hp2   = (float*)alloc((size_t)NN * 256 * 4);
    float* pa2   = (float*)alloc((size_t)NN * 256 * 4);
    float* pc2   = (float*)alloc((size_t)NN * 256 * 4);

    float* hno = (float*)d_out;
    float* heo = (float*)d_out + (size_t)NN * 64;

    const int SCAN_B = (NN + 1023) / 1024;
    hipMemsetAsync(cnt, 0, (size_t)NN * 4, stream);
    k_count<<<(NE + 255) / 256, 256, 0, stream>>>(dst, cnt);
    k_scanA<<<SCAN_B, 1024, 0, stream>>>(cnt, off, bsum);
    k_scanB<<<1, 64, 0, stream>>>(bsum, bbase, SCAN_B);
    k_scanC<<<SCAN_B, 1024, 0, stream>>>(off, cur, bbase);
    k_fill<<<(NE + 255) / 256, 256, 0, stream>>>(dst, cur, eid);
    k_convw<<<(128 * 64 + 256 * 128 + 255) / 256, 256, 0, stream>>>(We1, We2, W1b, W2b);
    k_perm<<<NE * 8 / 256, 256, 0, stream>>>(efeats, eid, src, dst, efb_p, src_p, dst_p);
    k_agg_ef<<<NN / 4, 256, 0, stream>>>(efb_p, off, hn1);
    k_nodeproj1<<<(NN + 31) / 32, 256, 0, stream>>>(hn1, Wn1, b1, We1, hp1, pa1, pc1);
    k_gemm1<<<NE / 64, 256, 0, stream>>>(efb_p, src_p, dst_p, W1b, Wa1, pa1, pc1, he1b, a1);
    k_agg1<<<NN / 4, 256, 0, stream>>>(a1, off, src_p, hp1, hn1o);
    dim3 g2((NN + 31) / 32, 3);
    k_nodeproj2<<<g2, 256, 0, stream>>>(hn1o, Wn2, b2, We2, hp2, pa2, pc2);
    k_gemm2<<<NE / 64, 256, 0, stream>>>(he1b, src_p, dst_p, eid, W2b, Wa2, pa2, pc2, heo, a1);
    k_agg2<<<NN / 4, 256, 0, stream>>>(a1, off, src_p, hp2, hno);
}

// Round 5
// 981.559 us; speedup vs baseline: 2.6886x; 1.0805x over previous
//
#include <hip/hip_runtime.h>
#include <math.h>

#define NN 30000
#define NE 480000

typedef short bf16x8 __attribute__((ext_vector_type(8)));
typedef float f32x4 __attribute__((ext_vector_type(4)));

static __device__ __forceinline__ unsigned short f2b(float f) {
    union { float f; unsigned u; } v; v.f = f;
    unsigned r = v.u + 0x7FFF + ((v.u >> 16) & 1);
    return (unsigned short)(r >> 16);
}

// Sum across the 16-lane DPP row (lanes c=0..15 of each 16-lane group).
// Hillis-Steele scan via row_shr; lane c==15 holds the full row sum.
static __device__ __forceinline__ float rowsum16(float v) {
    union { float f; int i; } u, t;
    u.f = v;
    t.i = __builtin_amdgcn_update_dpp(0, u.i, 0x111, 0xf, 0xf, true); u.f += t.f; // row_shr:1
    t.i = __builtin_amdgcn_update_dpp(0, u.i, 0x112, 0xf, 0xf, true); u.f += t.f; // row_shr:2
    t.i = __builtin_amdgcn_update_dpp(0, u.i, 0x114, 0xf, 0xf, true); u.f += t.f; // row_shr:4
    t.i = __builtin_amdgcn_update_dpp(0, u.i, 0x118, 0xf, 0xf, true); u.f += t.f; // row_shr:8
    return u.f;
}

// ---------------- CSR build (by dst) ----------------
__global__ void k_count(const int* __restrict__ dst, int* __restrict__ cnt) {
    int e = blockIdx.x * 256 + threadIdx.x;
    if (e < NE) atomicAdd(&cnt[dst[e]], 1);
}

__global__ __launch_bounds__(1024) void k_scanA(const int* __restrict__ cnt,
                                                int* __restrict__ off,
                                                int* __restrict__ bsum) {
    __shared__ int s[1024];
    int tid = threadIdx.x;
    int i = blockIdx.x * 1024 + tid;
    int v = (i < NN) ? cnt[i] : 0;
    s[tid] = v;
    __syncthreads();
    for (int d = 1; d < 1024; d <<= 1) {
        int t = (tid >= d) ? s[tid - d] : 0;
        __syncthreads();
        s[tid] += t;
        __syncthreads();
    }
    if (i < NN) off[i] = s[tid] - v;
    if (tid == 1023) bsum[blockIdx.x] = s[1023];
}

__global__ void k_scanB(const int* __restrict__ bsum, int* __restrict__ bbase, int nb) {
    if (threadIdx.x == 0) {
        int run = 0;
        for (int i = 0; i < nb; ++i) { bbase[i] = run; run += bsum[i]; }
    }
}

__global__ __launch_bounds__(1024) void k_scanC(int* __restrict__ off,
                                                int* __restrict__ cur,
                                                const int* __restrict__ bbase) {
    int i = blockIdx.x * 1024 + threadIdx.x;
    if (i < NN) {
        int o = off[i] + bbase[blockIdx.x];
        off[i] = o;
        cur[i] = o;
        if (i == 0) off[NN] = NE;
    }
}

__global__ void k_fill(const int* __restrict__ dst, int* __restrict__ cur,
                       int* __restrict__ eid) {
    int e = blockIdx.x * 256 + threadIdx.x;
    if (e < NE) {
        int p = atomicAdd(&cur[dst[e]], 1);
        eid[p] = e;
    }
}

// ---------------- permute edges into CSR order + convert ef to bf16 ----------------
__global__ void k_perm(const float* __restrict__ ef, const int* __restrict__ eid,
                       const int* __restrict__ src, const int* __restrict__ dst,
                       unsigned short* __restrict__ efb_p, int* __restrict__ src_p,
                       int* __restrict__ dst_p) {
    int gid = blockIdx.x * 256 + threadIdx.x;
    if (gid >= NE * 8) return;
    int i = gid >> 3, sub = gid & 7;
    int e = eid[i];
    if (sub == 0) { src_p[i] = src[e]; dst_p[i] = dst[e]; }
    const float4* p = (const float4*)(ef + (size_t)e * 64 + sub * 8);
    float4 x = p[0], y = p[1];
    uint4 o;
    o.x = (unsigned)f2b(x.x) | ((unsigned)f2b(x.y) << 16);
    o.y = (unsigned)f2b(x.z) | ((unsigned)f2b(x.w) << 16);
    o.z = (unsigned)f2b(y.x) | ((unsigned)f2b(y.y) << 16);
    o.w = (unsigned)f2b(y.z) | ((unsigned)f2b(y.w) << 16);
    *(uint4*)(efb_p + (size_t)i * 64 + sub * 8) = o;
}

__global__ void k_convw(const float* __restrict__ We1, const float* __restrict__ We2,
                        unsigned short* __restrict__ W1b, unsigned short* __restrict__ W2b) {
    int i = blockIdx.x * 256 + threadIdx.x;
    if (i < 128 * 64) {
        int r = i >> 6, k = i & 63;
        W1b[i] = f2b(We1[(size_t)r * 192 + 64 + k]);
    } else if (i < 128 * 64 + 256 * 128) {
        int j = i - 128 * 64;
        int r = j >> 7, k = j & 127;
        W2b[j] = f2b(We2[(size_t)r * 384 + 128 + k]);
    }
}

// ---------------- layer1: hn1[n] = sum of in-edge feats (fp32, gather via eid) ----------------
__global__ void k_agg_ef(const float* __restrict__ ef, const int* __restrict__ off,
                         const int* __restrict__ eid, float* __restrict__ hn1) {
    int w = (blockIdx.x * 256 + threadIdx.x) >> 6;
    int lane = threadIdx.x & 63;
    if (w >= NN) return;
    int s0 = off[w], s1 = off[w + 1];
    float acc = 0.f;
    for (int i = s0; i < s1; ++i) {
        int e = eid[i];
        acc += ef[(size_t)e * 64 + lane];
    }
    hn1[(size_t)w * 64 + lane] = acc;
}

// ---------------- node projections, layer1 -> fp32 tables hp1/pa1/pc1 (interleaved) ----------------
static __device__ __forceinline__ void store_p1(float* hp1, float* pa1,
                                                float* pc1, int n, int o, float v) {
    if (o < 128) {
        hp1[(size_t)n * 128 + (o & 63) * 2 + (o >> 6)] = v;
    } else if (o < 256) {
        int x = o - 128;
        pa1[(size_t)n * 128 + ((x >> 5) * 16 + (x & 15)) * 2 + ((x >> 4) & 1)] = v;
    } else {
        int x = o - 256;
        pc1[(size_t)n * 128 + ((x >> 5) * 16 + (x & 15)) * 2 + ((x >> 4) & 1)] = v;
    }
}

__global__ __launch_bounds__(256) void k_nodeproj1(
        const float* __restrict__ hn1, const float* __restrict__ Wn1,
        const float* __restrict__ b1, const float* __restrict__ We1,
        float* __restrict__ hp1, float* __restrict__ pa1,
        float* __restrict__ pc1) {
    __shared__ float Wl[384 * 68];
    __shared__ float Al[32 * 64];
    int tid = threadIdx.x;
    for (int t = tid; t < 384 * 16; t += 256) {
        int o = t >> 4, k4 = (t & 15) * 4;
        const float* sp;
        if (o < 128)      sp = &Wn1[o * 64 + k4];
        else if (o < 256) sp = &We1[(size_t)(o - 128) * 192 + k4];
        else              sp = &We1[(size_t)(o - 256) * 192 + 128 + k4];
        *(float4*)&Wl[o * 68 + k4] = *(const float4*)sp;
    }
    int nb = blockIdx.x * 32;
    for (int t = tid; t < 32 * 16; t += 256) {
        int r = t >> 4, k4 = (t & 15) * 4;
        int n = nb + r;
        float4 v = make_float4(0.f, 0.f, 0.f, 0.f);
        if (n < NN) v = *(const float4*)&hn1[(size_t)n * 64 + k4];
        *(float4*)&Al[r * 64 + k4] = v;
    }
    __syncthreads();
    int q = tid & 31, rg = tid >> 5;
    float acc[4][12];
    for (int i = 0; i < 4; ++i)
        for (int j = 0; j < 12; ++j) acc[i][j] = 0.f;
    for (int k4 = 0; k4 < 64; k4 += 4) {
        float4 a[4];
#pragma unroll
        for (int i = 0; i < 4; ++i) a[i] = *(float4*)&Al[(rg * 4 + i) * 64 + k4];
#pragma unroll
        for (int j = 0; j < 12; ++j) {
            float4 wv = *(float4*)&Wl[(q + 32 * j) * 68 + k4];
#pragma unroll
            for (int i = 0; i < 4; ++i)
                acc[i][j] += a[i].x * wv.x + a[i].y * wv.y + a[i].z * wv.z + a[i].w * wv.w;
        }
    }
    for (int i = 0; i < 4; ++i) {
        int n = nb + rg * 4 + i;
        if (n >= NN) continue;
        for (int j = 0; j < 12; ++j) {
            int o = q + 32 * j;
            float v = acc[i][j] + (o < 128 ? b1[o] : 0.f);
            store_p1(hp1, pa1, pc1, n, o, v);
        }
    }
}

// ---------------- edge GEMM layer1 (MFMA bf16, CSR order) ----------------
__global__ __launch_bounds__(256) void k_gemm1(
        const unsigned short* __restrict__ efb_p, const int* __restrict__ src_p,
        const int* __restrict__ dst_p, const unsigned short* __restrict__ W1b,
        const float* __restrict__ Wa1, const float* __restrict__ pa1,
        const float* __restrict__ pc1,
        unsigned short* __restrict__ he1b, float* __restrict__ a1) {
    int tid = threadIdx.x;
    int w = tid >> 6, l = tid & 63;
    int c = l & 15, g = l >> 4;
    int pb = blockIdx.x * 64;

    f32x4 acc[4][2];
    for (int m = 0; m < 4; ++m)
        for (int t = 0; t < 2; ++t) acc[m][t] = (f32x4)(0.f);

#pragma unroll
    for (int kk = 0; kk < 2; ++kk) {
        bf16x8 b[2];
#pragma unroll
        for (int t = 0; t < 2; ++t)
            b[t] = *(const bf16x8*)&W1b[(size_t)((2 * w + t) * 16 + c) * 64 + kk * 32 + g * 8];
#pragma unroll
        for (int m = 0; m < 4; ++m) {
            bf16x8 a = *(const bf16x8*)&efb_p[(size_t)(pb + m * 16 + c) * 64 + kk * 32 + g * 8];
#pragma unroll
            for (int t = 0; t < 2; ++t)
                acc[m][t] = __builtin_amdgcn_mfma_f32_16x16x32_bf16(a, b[t], acc[m][t], 0, 0, 0);
        }
    }

    float wsj0 = Wa1[c] + Wa1[32 + c] + Wa1[64 + c] + Wa1[96 + c];
    float wsj1 = Wa1[16 + c] + Wa1[48 + c] + Wa1[80 + c] + Wa1[112 + c];
    const float2* paF = (const float2*)pa1;
    const float2* pcF = (const float2*)pc1;

#pragma unroll
    for (int m = 0; m < 4; ++m) {
#pragma unroll
        for (int r = 0; r < 4; ++r) {
            int pos = pb + m * 16 + g * 4 + r;
            int s = src_p[pos], d = dst_p[pos];
            float2 ua = paF[(size_t)s * 64 + w * 16 + c];
            float2 uc = pcF[(size_t)d * 64 + w * 16 + c];
            float f0 = acc[m][0][r] + ua.x + uc.x;
            float f1 = acc[m][1][r] + ua.y + uc.y;
            float lf0 = (f0 > 0.f) ? f0 : 0.01f * f0;
            float lf1 = (f1 > 0.f) ? f1 : 0.01f * f1;
            float av = lf0 * wsj0 + lf1 * wsj1;
            he1b[(size_t)pos * 128 + w * 32 + c]      = f2b((lf0 > 0.f) ? lf0 : expm1f(lf0));
            he1b[(size_t)pos * 128 + w * 32 + 16 + c] = f2b((lf1 > 0.f) ? lf1 : expm1f(lf1));
            av = rowsum16(av);
            if (c == 15) a1[(size_t)pos * 4 + w] = av;
        }
    }
}

// ---------------- segment softmax + weighted aggregate, layer1 ----------------
__global__ void k_agg1(const float* __restrict__ a1, const int* __restrict__ off,
                       const int* __restrict__ src_p, const float* __restrict__ hp1,
                       float* __restrict__ hn1o) {
    __shared__ float4 alf[4][64];
    int wv = threadIdx.x >> 6;
    int w = (blockIdx.x * 256 + threadIdx.x) >> 6;
    int lane = threadIdx.x & 63;
    if (w >= NN) return;
    int s0 = off[w], s1 = off[w + 1];
    if (s1 == s0) {
        hn1o[(size_t)w * 128 + lane] = 0.f;
        hn1o[(size_t)w * 128 + 64 + lane] = 0.f;
        return;
    }
    float m[4] = {-INFINITY, -INFINITY, -INFINITY, -INFINITY};
    for (int i = s0 + lane; i < s1; i += 64) {
        float4 av = *(const float4*)&a1[(size_t)i * 4];
        m[0] = fmaxf(m[0], av.x); m[1] = fmaxf(m[1], av.y);
        m[2] = fmaxf(m[2], av.z); m[3] = fmaxf(m[3], av.w);
    }
#pragma unroll
    for (int d = 1; d < 64; d <<= 1) {
        m[0] = fmaxf(m[0], __shfl_xor(m[0], d, 64));
        m[1] = fmaxf(m[1], __shfl_xor(m[1], d, 64));
        m[2] = fmaxf(m[2], __shfl_xor(m[2], d, 64));
        m[3] = fmaxf(m[3], __shfl_xor(m[3], d, 64));
    }
    float den[4] = {0.f, 0.f, 0.f, 0.f};
    for (int i = s0 + lane; i < s1; i += 64) {
        float4 av = *(const float4*)&a1[(size_t)i * 4];
        den[0] += expf(av.x - m[0]); den[1] += expf(av.y - m[1]);
        den[2] += expf(av.z - m[2]); den[3] += expf(av.w - m[3]);
    }
#pragma unroll
    for (int d = 1; d < 64; d <<= 1) {
        den[0] += __shfl_xor(den[0], d, 64);
        den[1] += __shfl_xor(den[1], d, 64);
        den[2] += __shfl_xor(den[2], d, 64);
        den[3] += __shfl_xor(den[3], d, 64);
    }
    float r0 = 1.f / den[0], r1 = 1.f / den[1], r2 = 1.f / den[2], r3 = 1.f / den[3];
    int h0 = lane >> 5;
    const float2* hpF = (const float2*)hp1;
    float acc0 = 0.f, acc1 = 0.f;
    for (int base = s0; base < s1; base += 64) {
        int i = base + lane;
        if (i < s1) {
            float4 av = *(const float4*)&a1[(size_t)i * 4];
            float4 al;
            al.x = expf(av.x - m[0]) * r0;
            al.y = expf(av.y - m[1]) * r1;
            al.z = expf(av.z - m[2]) * r2;
            al.w = expf(av.w - m[3]) * r3;
            alf[wv][lane] = al;
        }
        int lim = s1 - base; if (lim > 64) lim = 64;
        for (int k = 0; k < lim; ++k) {
            float4 al = alf[wv][k];
            int s = src_p[base + k];
            float2 u = hpF[(size_t)s * 64 + lane];
            float w0 = (h0 == 0) ? al.x : al.y;
            float w1 = (h0 == 0) ? al.z : al.w;
            acc0 += w0 * u.x;
            acc1 += w1 * u.y;
        }
    }
    float e0 = (acc0 > 0.f) ? acc0 : expm1f(acc0);
    float e1 = (acc1 > 0.f) ? acc1 : expm1f(acc1);
    hn1o[(size_t)w * 128 + lane] = e0;
    hn1o[(size_t)w * 128 + 64 + lane] = e1;
}

// ---------------- node projections, layer2 -> fp32 tables hp2/pa2/pc2 (interleaved) ----------------
static __device__ __forceinline__ void store_p2(float* hp2, float* pa2,
                                                float* pc2, int n, int o, float v) {
    if (o < 256) {
        hp2[(size_t)n * 256 + (o & 63) * 4 + (o >> 6)] = v;
    } else if (o < 512) {
        int x = o - 256;
        pa2[(size_t)n * 256 + (x & 63) * 4 + (x >> 6)] = v;
    } else {
        int x = o - 512;
        pc2[(size_t)n * 256 + (x & 63) * 4 + (x >> 6)] = v;
    }
}

__global__ __launch_bounds__(256) void k_nodeproj2(
        const float* __restrict__ hn1o, const float* __restrict__ Wn2,
        const float* __restrict__ b2, const float* __restrict__ We2,
        float* __restrict__ hp2, float* __restrict__ pa2,
        float* __restrict__ pc2) {
    __shared__ float Wl[256 * 132];
    __shared__ float Al[32 * 128];
    int tid = threadIdx.x;
    int seg = blockIdx.y;
    for (int t = tid; t < 256 * 32; t += 256) {
        int o = t >> 5, k4 = (t & 31) * 4;
        int og = seg * 256 + o;
        const float* sp;
        if (og < 256)      sp = &Wn2[(size_t)og * 128 + k4];
        else if (og < 512) sp = &We2[(size_t)(og - 256) * 384 + k4];
        else               sp = &We2[(size_t)(og - 512) * 384 + 256 + k4];
        *(float4*)&Wl[o * 132 + k4] = *(const float4*)sp;
    }
    int nb = blockIdx.x * 32;
    for (int t = tid; t < 32 * 32; t += 256) {
        int r = t >> 5, k4 = (t & 31) * 4;
        int n = nb + r;
        float4 v = make_float4(0.f, 0.f, 0.f, 0.f);
        if (n < NN) v = *(const float4*)&hn1o[(size_t)n * 128 + k4];
        *(float4*)&Al[r * 128 + k4] = v;
    }
    __syncthreads();
    int q = tid & 31, rg = tid >> 5;
    float acc[4][8];
    for (int i = 0; i < 4; ++i)
        for (int j = 0; j < 8; ++j) acc[i][j] = 0.f;
    for (int k4 = 0; k4 < 128; k4 += 4) {
        float4 a[4];
#pragma unroll
        for (int i = 0; i < 4; ++i) a[i] = *(float4*)&Al[(rg * 4 + i) * 128 + k4];
#pragma unroll
        for (int j = 0; j < 8; ++j) {
            float4 wv = *(float4*)&Wl[(q + 32 * j) * 132 + k4];
#pragma unroll
            for (int i = 0; i < 4; ++i)
                acc[i][j] += a[i].x * wv.x + a[i].y * wv.y + a[i].z * wv.z + a[i].w * wv.w;
        }
    }
    for (int i = 0; i < 4; ++i) {
        int n = nb + rg * 4 + i;
        if (n >= NN) continue;
        for (int j = 0; j < 8; ++j) {
            int og = seg * 256 + q + 32 * j;
            float v = acc[i][j] + (og < 256 ? b2[og] : 0.f);
            store_p2(hp2, pa2, pc2, n, og, v);
        }
    }
}

// ---------------- edge GEMM layer2 (MFMA bf16, CSR order): a2 + heo ----------------
__global__ __launch_bounds__(256) void k_gemm2(
        const unsigned short* __restrict__ he1b, const int* __restrict__ src_p,
        const int* __restrict__ dst_p, const int* __restrict__ eid,
        const unsigned short* __restrict__ W2b, const float* __restrict__ Wa2,
        const float* __restrict__ pa2, const float* __restrict__ pc2,
        float* __restrict__ heo, float* __restrict__ a2) {
    __shared__ float a2l[4 * 64 * 4];
    int tid = threadIdx.x;
    int w = tid >> 6, l = tid & 63;
    int c = l & 15, g = l >> 4;
    int j = w * 16 + c;
    int pb = blockIdx.x * 64;

    f32x4 acc[4][4];
    for (int m = 0; m < 4; ++m)
        for (int t = 0; t < 4; ++t) acc[m][t] = (f32x4)(0.f);

#pragma unroll
    for (int kk = 0; kk < 4; ++kk) {
        bf16x8 b[4];
#pragma unroll
        for (int t = 0; t < 4; ++t)
            b[t] = *(const bf16x8*)&W2b[(size_t)((w + 4 * t) * 16 + c) * 128 + kk * 32 + g * 8];
#pragma unroll
        for (int m = 0; m < 4; ++m) {
            bf16x8 a = *(const bf16x8*)&he1b[(size_t)(pb + m * 16 + c) * 128 + kk * 32 + g * 8];
#pragma unroll
            for (int t = 0; t < 4; ++t)
                acc[m][t] = __builtin_amdgcn_mfma_f32_16x16x32_bf16(a, b[t], acc[m][t], 0, 0, 0);
        }
    }

    float wsj = Wa2[j] + Wa2[64 + j] + Wa2[128 + j] + Wa2[192 + j];
    const float4* paF = (const float4*)pa2;
    const float4* pcF = (const float4*)pc2;

#pragma unroll
    for (int m = 0; m < 4; ++m) {
#pragma unroll
        for (int r = 0; r < 4; ++r) {
            int le = m * 16 + g * 4 + r;
            int pos = pb + le;
            int s = src_p[pos], d = dst_p[pos];
            int e = eid[pos];
            float4 ua = paF[(size_t)s * 64 + j];
            float4 uc = pcF[(size_t)d * 64 + j];
            float f[4];
            f[0] = acc[m][0][r] + ua.x + uc.x;
            f[1] = acc[m][1][r] + ua.y + uc.y;
            f[2] = acc[m][2][r] + ua.z + uc.z;
            f[3] = acc[m][3][r] + ua.w + uc.w;
            float hsum = 0.f;
            float avt[4];
#pragma unroll
            for (int t = 0; t < 4; ++t) {
                float lf = (f[t] > 0.f) ? f[t] : 0.01f * f[t];
                hsum += lf;
                avt[t] = lf * wsj;
            }
#pragma unroll
            for (int t = 0; t < 4; ++t) avt[t] = rowsum16(avt[t]);
            if (c == 15) {
                float4 st = make_float4(avt[0], avt[1], avt[2], avt[3]);
                *(float4*)&a2l[(w * 64 + le) * 4] = st;
            }
            heo[(size_t)e * 64 + j] = 0.25f * hsum;
        }
    }
    __syncthreads();
    {
        int pos = tid >> 2, t = tid & 3;
        float v = a2l[(0 * 64 + pos) * 4 + t] + a2l[(1 * 64 + pos) * 4 + t]
                + a2l[(2 * 64 + pos) * 4 + t] + a2l[(3 * 64 + pos) * 4 + t];
        a2[(size_t)(pb + pos) * 4 + t] = v;
    }
}

// ---------------- segment softmax + aggregate + head-mean, layer2 ----------------
__global__ void k_agg2(const float* __restrict__ a2, const int* __restrict__ off,
                       const int* __restrict__ src_p, const float* __restrict__ hp2,
                       float* __restrict__ hno) {
    __shared__ float4 alf[4][64];
    int wv = threadIdx.x >> 6;
    int w = (blockIdx.x * 256 + threadIdx.x) >> 6;
    int lane = threadIdx.x & 63;
    if (w >= NN) return;
    int s0 = off[w], s1 = off[w + 1];
    if (s1 == s0) {
        hno[(size_t)w * 64 + lane] = 0.f;
        return;
    }
    float m[4] = {-INFINITY, -INFINITY, -INFINITY, -INFINITY};
    for (int i = s0 + lane; i < s1; i += 64) {
        float4 av = *(const float4*)&a2[(size_t)i * 4];
        m[0] = fmaxf(m[0], av.x); m[1] = fmaxf(m[1], av.y);
        m[2] = fmaxf(m[2], av.z); m[3] = fmaxf(m[3], av.w);
    }
#pragma unroll
    for (int d = 1; d < 64; d <<= 1) {
        m[0] = fmaxf(m[0], __shfl_xor(m[0], d, 64));
        m[1] = fmaxf(m[1], __shfl_xor(m[1], d, 64));
        m[2] = fmaxf(m[2], __shfl_xor(m[2], d, 64));
        m[3] = fmaxf(m[3], __shfl_xor(m[3], d, 64));
    }
    float den[4] = {0.f, 0.f, 0.f, 0.f};
    for (int i = s0 + lane; i < s1; i += 64) {
        float4 av = *(const float4*)&a2[(size_t)i * 4];
        den[0] += expf(av.x - m[0]); den[1] += expf(av.y - m[1]);
        den[2] += expf(av.z - m[2]); den[3] += expf(av.w - m[3]);
    }
#pragma unroll
    for (int d = 1; d < 64; d <<= 1) {
        den[0] += __shfl_xor(den[0], d, 64);
        den[1] += __shfl_xor(den[1], d, 64);
        den[2] += __shfl_xor(den[2], d, 64);
        den[3] += __shfl_xor(den[3], d, 64);
    }
    float r0 = 1.f / den[0], r1 = 1.f / den[1], r2 = 1.f / den[2], r3 = 1.f / den[3];
    const float4* hpF = (const float4*)hp2;
    float acc0 = 0.f, acc1 = 0.f, acc2 = 0.f, acc3 = 0.f;
    for (int base = s0; base < s1; base += 64) {
        int i = base + lane;
        if (i < s1) {
            float4 av = *(const float4*)&a2[(size_t)i * 4];
            float4 al;
            al.x = expf(av.x - m[0]) * r0;
            al.y = expf(av.y - m[1]) * r1;
            al.z = expf(av.z - m[2]) * r2;
            al.w = expf(av.w - m[3]) * r3;
            alf[wv][lane] = al;
        }
        int lim = s1 - base; if (lim > 64) lim = 64;
        for (int k = 0; k < lim; ++k) {
            float4 al = alf[wv][k];
            int s = src_p[base + k];
            float4 u = hpF[(size_t)s * 64 + lane];
            acc0 += al.x * u.x;
            acc1 += al.y * u.y;
            acc2 += al.z * u.z;
            acc3 += al.w * u.w;
        }
    }
    hno[(size_t)w * 64 + lane] = 0.25f * (acc0 + acc1 + acc2 + acc3);
}

extern "C" void kernel_launch(void* const* d_in, const int* in_sizes, int n_in,
                              void* d_out, int out_size, void* d_ws, size_t ws_size,
                              hipStream_t stream) {
    const float* efeats = (const float*)d_in[1];
    const int* src = (const int*)d_in[2];
    const int* dst = (const int*)d_in[3];
    const float* Wn1 = (const float*)d_in[4];
    const float* b1  = (const float*)d_in[5];
    const float* We1 = (const float*)d_in[6];
    const float* Wa1 = (const float*)d_in[7];
    const float* Wn2 = (const float*)d_in[8];
    const float* b2  = (const float*)d_in[9];
    const float* We2 = (const float*)d_in[10];
    const float* Wa2 = (const float*)d_in[11];

    char* ws = (char*)d_ws;
    size_t o = 0;
    auto alloc = [&](size_t bytes) {
        void* p = ws + o;
        o += (bytes + 255) & ~(size_t)255;
        return p;
    };
    int* cnt   = (int*)alloc((size_t)NN * 4);
    int* off   = (int*)alloc((size_t)(NN + 1) * 4);
    int* cur   = (int*)alloc((size_t)NN * 4);
    int* eid   = (int*)alloc((size_t)NE * 4);
    int* src_p = (int*)alloc((size_t)NE * 4);
    int* dst_p = (int*)alloc((size_t)NE * 4);
    int* bsum  = (int*)alloc(64 * 4);
    int* bbase = (int*)alloc(64 * 4);
    float* hn1 = (float*)alloc((size_t)NN * 64 * 4);
    float* hn1o= (float*)alloc((size_t)NN * 128 * 4);
    float* a1  = (float*)alloc((size_t)NE * 4 * 4);   // reused as a2
    unsigned short* efb_p = (unsigned short*)alloc((size_t)NE * 64 * 2);
    unsigned short* he1b  = (unsigned short*)alloc((size_t)NE * 128 * 2);
    unsigned short* W1b   = (unsigned short*)alloc((size_t)128 * 64 * 2);
    unsigned short* W2b   = (unsigned short*)alloc((size_t)256 * 128 * 2);
    float* hp1   = (float*)alloc((size_t)NN * 128 * 4);
    float* pa1   = (float*)alloc((size_t)NN * 128 * 4);
    float* pc1   = (float*)alloc((size_t)NN * 128 * 4);
    float* hp2   = (float*)alloc((size_t)NN * 256 * 4);
    float* pa2   = (float*)alloc((size_t)NN * 256 * 4);
    float* pc2   = (float*)alloc((size_t)NN * 256 * 4);

    float* hno = (float*)d_out;
    float* heo = (float*)d_out + (size_t)NN * 64;

    const int SCAN_B = (NN + 1023) / 1024;
    hipMemsetAsync(cnt, 0, (size_t)NN * 4, stream);
    k_count<<<(NE + 255) / 256, 256, 0, stream>>>(dst, cnt);
    k_scanA<<<SCAN_B, 1024, 0, stream>>>(cnt, off, bsum);
    k_scanB<<<1, 64, 0, stream>>>(bsum, bbase, SCAN_B);
    k_scanC<<<SCAN_B, 1024, 0, stream>>>(off, cur, bbase);
    k_fill<<<(NE + 255) / 256, 256, 0, stream>>>(dst, cur, eid);
    k_convw<<<(128 * 64 + 256 * 128 + 255) / 256, 256, 0, stream>>>(We1, We2, W1b, W2b);
    k_perm<<<NE * 8 / 256, 256, 0, stream>>>(efeats, eid, src, dst, efb_p, src_p, dst_p);
    k_agg_ef<<<NN / 4, 256, 0, stream>>>(efeats, off, eid, hn1);
    k_nodeproj1<<<(NN + 31) / 32, 256, 0, stream>>>(hn1, Wn1, b1, We1, hp1, pa1, pc1);
    k_gemm1<<<NE / 64, 256, 0, stream>>>(efb_p, src_p, dst_p, W1b, Wa1, pa1, pc1, he1b, a1);
    k_agg1<<<NN / 4, 256, 0, stream>>>(a1, off, src_p, hp1, hn1o);
    dim3 g2((NN + 31) / 32, 3);
    k_nodeproj2<<<g2, 256, 0, stream>>>(hn1o, Wn2, b2, We2, hp2, pa2, pc2);
    k_gemm2<<<NE / 64, 256, 0, stream>>>(he1b, src_p, dst_p, eid, W2b, Wa2, pa2, pc2, heo, a1);
    k_agg2<<<NN / 4, 256, 0, stream>>>(a1, off, src_p, hp2, hno);
}

// Round 7
// 827.825 us; speedup vs baseline: 3.1879x; 1.1857x over previous
//
#include <hip/hip_runtime.h>
#include <math.h>

#define NN 30000
#define NE 480000

typedef short bf16x8 __attribute__((ext_vector_type(8)));
typedef float f32x4 __attribute__((ext_vector_type(4)));

static __device__ __forceinline__ unsigned short f2b(float f) {
    union { float f; unsigned u; } v; v.f = f;
    unsigned r = v.u + 0x7FFF + ((v.u >> 16) & 1);
    return (unsigned short)(r >> 16);
}
static __device__ __forceinline__ float b2f(unsigned short s) {
    union { unsigned u; float f; } v; v.u = ((unsigned)s) << 16; return v.f;
}

// Sum across the 16-lane DPP row; lane c==15 holds the full row sum.
static __device__ __forceinline__ float rowsum16(float v) {
    union { float f; int i; } u, t;
    u.f = v;
    t.i = __builtin_amdgcn_update_dpp(0, u.i, 0x111, 0xf, 0xf, true); u.f += t.f;
    t.i = __builtin_amdgcn_update_dpp(0, u.i, 0x112, 0xf, 0xf, true); u.f += t.f;
    t.i = __builtin_amdgcn_update_dpp(0, u.i, 0x114, 0xf, 0xf, true); u.f += t.f;
    t.i = __builtin_amdgcn_update_dpp(0, u.i, 0x118, 0xf, 0xf, true); u.f += t.f;
    return u.f;
}

// ---------------- CSR build (by dst) ----------------
__global__ void k_count(const int* __restrict__ dst, int* __restrict__ cnt) {
    int e = blockIdx.x * 256 + threadIdx.x;
    if (e < NE) atomicAdd(&cnt[dst[e]], 1);
}

__global__ __launch_bounds__(1024) void k_scanA(const int* __restrict__ cnt,
                                                int* __restrict__ off,
                                                int* __restrict__ bsum) {
    __shared__ int s[1024];
    int tid = threadIdx.x;
    int i = blockIdx.x * 1024 + tid;
    int v = (i < NN) ? cnt[i] : 0;
    s[tid] = v;
    __syncthreads();
    for (int d = 1; d < 1024; d <<= 1) {
        int t = (tid >= d) ? s[tid - d] : 0;
        __syncthreads();
        s[tid] += t;
        __syncthreads();
    }
    if (i < NN) off[i] = s[tid] - v;
    if (tid == 1023) bsum[blockIdx.x] = s[1023];
}

__global__ void k_scanB(const int* __restrict__ bsum, int* __restrict__ bbase, int nb) {
    if (threadIdx.x == 0) {
        int run = 0;
        for (int i = 0; i < nb; ++i) { bbase[i] = run; run += bsum[i]; }
    }
}

__global__ __launch_bounds__(1024) void k_scanC(int* __restrict__ off,
                                                int* __restrict__ cur,
                                                const int* __restrict__ bbase) {
    int i = blockIdx.x * 1024 + threadIdx.x;
    if (i < NN) {
        int o = off[i] + bbase[blockIdx.x];
        off[i] = o;
        cur[i] = o;
        if (i == 0) off[NN] = NE;
    }
}

__global__ void k_fill(const int* __restrict__ dst, int* __restrict__ cur,
                       int* __restrict__ eid) {
    int e = blockIdx.x * 256 + threadIdx.x;
    if (e < NE) {
        int p = atomicAdd(&cur[dst[e]], 1);
        eid[p] = e;
    }
}

// ---------------- permute edges into CSR order + convert ef to bf16 ----------------
__global__ void k_perm(const float* __restrict__ ef, const int* __restrict__ eid,
                       const int* __restrict__ src, const int* __restrict__ dst,
                       unsigned short* __restrict__ efb_p, int* __restrict__ src_p,
                       int* __restrict__ dst_p) {
    int gid = blockIdx.x * 256 + threadIdx.x;
    if (gid >= NE * 8) return;
    int i = gid >> 3, sub = gid & 7;
    int e = eid[i];
    if (sub == 0) { src_p[i] = src[e]; dst_p[i] = dst[e]; }
    const float4* p = (const float4*)(ef + (size_t)e * 64 + sub * 8);
    float4 x = p[0], y = p[1];
    uint4 o;
    o.x = (unsigned)f2b(x.x) | ((unsigned)f2b(x.y) << 16);
    o.y = (unsigned)f2b(x.z) | ((unsigned)f2b(x.w) << 16);
    o.z = (unsigned)f2b(y.x) | ((unsigned)f2b(y.y) << 16);
    o.w = (unsigned)f2b(y.z) | ((unsigned)f2b(y.w) << 16);
    *(uint4*)(efb_p + (size_t)i * 64 + sub * 8) = o;
}

// edge-GEMM weights (single bf16)
__global__ void k_convw(const float* __restrict__ We1, const float* __restrict__ We2,
                        unsigned short* __restrict__ W1b, unsigned short* __restrict__ W2b) {
    int i = blockIdx.x * 256 + threadIdx.x;
    if (i < 128 * 64) {
        int r = i >> 6, k = i & 63;
        W1b[i] = f2b(We1[(size_t)r * 192 + 64 + k]);
    } else if (i < 128 * 64 + 256 * 128) {
        int j = i - 128 * 64;
        int r = j >> 7, k = j & 127;
        W2b[j] = f2b(We2[(size_t)r * 384 + 128 + k]);
    }
}

// node-proj weights, split hi/lo bf16.
// W1cat [384][64]: rows 0..127 Wn1, 128..255 We1[:,0:64], 256..383 We1[:,128:192]
// W2cat [768][128]: rows 0..255 Wn2, 256..511 We2[:,0:128], 512..767 We2[:,256:384]
__global__ void k_convsplit(const float* __restrict__ Wn1, const float* __restrict__ We1,
                            const float* __restrict__ Wn2, const float* __restrict__ We2,
                            unsigned short* __restrict__ W1h, unsigned short* __restrict__ W1l,
                            unsigned short* __restrict__ W2h, unsigned short* __restrict__ W2l) {
    int i = blockIdx.x * 256 + threadIdx.x;
    if (i < 384 * 64) {
        int r = i >> 6, k = i & 63;
        float v;
        if (r < 128)      v = Wn1[(size_t)r * 64 + k];
        else if (r < 256) v = We1[(size_t)(r - 128) * 192 + k];
        else              v = We1[(size_t)(r - 256) * 192 + 128 + k];
        unsigned short h = f2b(v);
        W1h[i] = h; W1l[i] = f2b(v - b2f(h));
    } else if (i < 384 * 64 + 768 * 128) {
        int j = i - 384 * 64;
        int r = j >> 7, k = j & 127;
        float v;
        if (r < 256)      v = Wn2[(size_t)r * 128 + k];
        else if (r < 512) v = We2[(size_t)(r - 256) * 384 + k];
        else              v = We2[(size_t)(r - 512) * 384 + 256 + k];
        unsigned short h = f2b(v);
        W2h[j] = h; W2l[j] = f2b(v - b2f(h));
    }
}

// ---------------- layer1: hn1 = sum of in-edge feats (fp32 gather) -> hi/lo bf16 ----------------
__global__ void k_agg_ef(const float* __restrict__ ef, const int* __restrict__ off,
                         const int* __restrict__ eid,
                         unsigned short* __restrict__ hn1h, unsigned short* __restrict__ hn1l) {
    int w = (blockIdx.x * 256 + threadIdx.x) >> 6;
    int lane = threadIdx.x & 63;
    if (w >= NN) return;
    int s0 = off[w], s1 = off[w + 1];
    float acc = 0.f;
    for (int i = s0; i < s1; ++i) {
        int e = eid[i];
        acc += ef[(size_t)e * 64 + lane];
    }
    unsigned short h = f2b(acc);
    hn1h[(size_t)w * 64 + lane] = h;
    hn1l[(size_t)w * 64 + lane] = f2b(acc - b2f(h));
}

// ---------------- fp32 table store helpers (interleaved layouts for gathers) ----------------
static __device__ __forceinline__ void store_p1(float* hp1, float* pa1,
                                                float* pc1, int n, int o, float v) {
    if (o < 128) {
        hp1[(size_t)n * 128 + (o & 63) * 2 + (o >> 6)] = v;
    } else if (o < 256) {
        int x = o - 128;
        pa1[(size_t)n * 128 + ((x >> 5) * 16 + (x & 15)) * 2 + ((x >> 4) & 1)] = v;
    } else {
        int x = o - 256;
        pc1[(size_t)n * 128 + ((x >> 5) * 16 + (x & 15)) * 2 + ((x >> 4) & 1)] = v;
    }
}

static __device__ __forceinline__ void store_p2(float* hp2, float* pa2,
                                                float* pc2, int n, int o, float v) {
    if (o < 256) {
        hp2[(size_t)n * 256 + (o & 63) * 4 + (o >> 6)] = v;
    } else if (o < 512) {
        int x = o - 256;
        pa2[(size_t)n * 256 + (x & 63) * 4 + (x >> 6)] = v;
    } else {
        int x = o - 512;
        pc2[(size_t)n * 256 + (x & 63) * 4 + (x >> 6)] = v;
    }
}

// ---------------- node projections layer1 (split-bf16 MFMA, no LDS) ----------------
// 16 nodes per block (shared A-tile); wave w owns output columns [w*96, w*96+96)
__global__ __launch_bounds__(256) void k_nodeproj1(
        const unsigned short* __restrict__ hn1h, const unsigned short* __restrict__ hn1l,
        const unsigned short* __restrict__ W1h, const unsigned short* __restrict__ W1l,
        const float* __restrict__ b1,
        float* __restrict__ hp1, float* __restrict__ pa1, float* __restrict__ pc1) {
    int tid = threadIdx.x;
    int w = tid >> 6, l = tid & 63;
    int c = l & 15, g = l >> 4;
    int pb = blockIdx.x * 16;

    f32x4 acc[6];
#pragma unroll
    for (int t = 0; t < 6; ++t) acc[t] = (f32x4)(0.f);

#pragma unroll
    for (int kk = 0; kk < 2; ++kk) {
        int arow = pb + c;
        bf16x8 ah = *(const bf16x8*)&hn1h[(size_t)arow * 64 + kk * 32 + g * 8];
        bf16x8 al = *(const bf16x8*)&hn1l[(size_t)arow * 64 + kk * 32 + g * 8];
#pragma unroll
        for (int t = 0; t < 6; ++t) {
            int brow = w * 96 + t * 16 + c;
            bf16x8 bh = *(const bf16x8*)&W1h[(size_t)brow * 64 + kk * 32 + g * 8];
            bf16x8 bl = *(const bf16x8*)&W1l[(size_t)brow * 64 + kk * 32 + g * 8];
            acc[t] = __builtin_amdgcn_mfma_f32_16x16x32_bf16(ah, bh, acc[t], 0, 0, 0);
            acc[t] = __builtin_amdgcn_mfma_f32_16x16x32_bf16(ah, bl, acc[t], 0, 0, 0);
            acc[t] = __builtin_amdgcn_mfma_f32_16x16x32_bf16(al, bh, acc[t], 0, 0, 0);
        }
    }

#pragma unroll
    for (int t = 0; t < 6; ++t) {
        int og = w * 96 + t * 16 + c;
        float bias = (og < 128) ? b1[og] : 0.f;
#pragma unroll
        for (int r = 0; r < 4; ++r) {
            int n = pb + g * 4 + r;
            if (n < NN) store_p1(hp1, pa1, pc1, n, og, acc[t][r] + bias);
        }
    }
}

// ---------------- edge GEMM layer1 (MFMA bf16, CSR order) ----------------
__global__ __launch_bounds__(256) void k_gemm1(
        const unsigned short* __restrict__ efb_p, const int* __restrict__ src_p,
        const int* __restrict__ dst_p, const unsigned short* __restrict__ W1b,
        const float* __restrict__ Wa1, const float* __restrict__ pa1,
        const float* __restrict__ pc1,
        unsigned short* __restrict__ he1b, float* __restrict__ a1) {
    int tid = threadIdx.x;
    int w = tid >> 6, l = tid & 63;
    int c = l & 15, g = l >> 4;
    int pb = blockIdx.x * 64;

    f32x4 acc[4][2];
    for (int m = 0; m < 4; ++m)
        for (int t = 0; t < 2; ++t) acc[m][t] = (f32x4)(0.f);

#pragma unroll
    for (int kk = 0; kk < 2; ++kk) {
        bf16x8 b[2];
#pragma unroll
        for (int t = 0; t < 2; ++t)
            b[t] = *(const bf16x8*)&W1b[(size_t)((2 * w + t) * 16 + c) * 64 + kk * 32 + g * 8];
#pragma unroll
        for (int m = 0; m < 4; ++m) {
            bf16x8 a = *(const bf16x8*)&efb_p[(size_t)(pb + m * 16 + c) * 64 + kk * 32 + g * 8];
#pragma unroll
            for (int t = 0; t < 2; ++t)
                acc[m][t] = __builtin_amdgcn_mfma_f32_16x16x32_bf16(a, b[t], acc[m][t], 0, 0, 0);
        }
    }

    float wsj0 = Wa1[c] + Wa1[32 + c] + Wa1[64 + c] + Wa1[96 + c];
    float wsj1 = Wa1[16 + c] + Wa1[48 + c] + Wa1[80 + c] + Wa1[112 + c];
    const float2* paF = (const float2*)pa1;
    const float2* pcF = (const float2*)pc1;

#pragma unroll
    for (int m = 0; m < 4; ++m) {
#pragma unroll
        for (int r = 0; r < 4; ++r) {
            int pos = pb + m * 16 + g * 4 + r;
            int s = src_p[pos], d = dst_p[pos];
            float2 ua = paF[(size_t)s * 64 + w * 16 + c];
            float2 uc = pcF[(size_t)d * 64 + w * 16 + c];
            float f0 = acc[m][0][r] + ua.x + uc.x;
            float f1 = acc[m][1][r] + ua.y + uc.y;
            float lf0 = (f0 > 0.f) ? f0 : 0.01f * f0;
            float lf1 = (f1 > 0.f) ? f1 : 0.01f * f1;
            float av = lf0 * wsj0 + lf1 * wsj1;
            he1b[(size_t)pos * 128 + w * 32 + c]      = f2b((lf0 > 0.f) ? lf0 : expm1f(lf0));
            he1b[(size_t)pos * 128 + w * 32 + 16 + c] = f2b((lf1 > 0.f) ? lf1 : expm1f(lf1));
            av = rowsum16(av);
            if (c == 15) a1[(size_t)pos * 4 + w] = av;
        }
    }
}

// ---------------- segment softmax + weighted aggregate, layer1 -> hi/lo bf16 ----------------
__global__ void k_agg1(const float* __restrict__ a1, const int* __restrict__ off,
                       const int* __restrict__ src_p, const float* __restrict__ hp1,
                       unsigned short* __restrict__ hn1oh, unsigned short* __restrict__ hn1ol) {
    __shared__ float4 alf[4][64];
    int wv = threadIdx.x >> 6;
    int w = (blockIdx.x * 256 + threadIdx.x) >> 6;
    int lane = threadIdx.x & 63;
    if (w >= NN) return;
    int s0 = off[w], s1 = off[w + 1];
    if (s1 == s0) {
        hn1oh[(size_t)w * 128 + lane] = 0; hn1oh[(size_t)w * 128 + 64 + lane] = 0;
        hn1ol[(size_t)w * 128 + lane] = 0; hn1ol[(size_t)w * 128 + 64 + lane] = 0;
        return;
    }
    float m[4] = {-INFINITY, -INFINITY, -INFINITY, -INFINITY};
    for (int i = s0 + lane; i < s1; i += 64) {
        float4 av = *(const float4*)&a1[(size_t)i * 4];
        m[0] = fmaxf(m[0], av.x); m[1] = fmaxf(m[1], av.y);
        m[2] = fmaxf(m[2], av.z); m[3] = fmaxf(m[3], av.w);
    }
#pragma unroll
    for (int d = 1; d < 64; d <<= 1) {
        m[0] = fmaxf(m[0], __shfl_xor(m[0], d, 64));
        m[1] = fmaxf(m[1], __shfl_xor(m[1], d, 64));
        m[2] = fmaxf(m[2], __shfl_xor(m[2], d, 64));
        m[3] = fmaxf(m[3], __shfl_xor(m[3], d, 64));
    }
    float den[4] = {0.f, 0.f, 0.f, 0.f};
    for (int i = s0 + lane; i < s1; i += 64) {
        float4 av = *(const float4*)&a1[(size_t)i * 4];
        den[0] += expf(av.x - m[0]); den[1] += expf(av.y - m[1]);
        den[2] += expf(av.z - m[2]); den[3] += expf(av.w - m[3]);
    }
#pragma unroll
    for (int d = 1; d < 64; d <<= 1) {
        den[0] += __shfl_xor(den[0], d, 64);
        den[1] += __shfl_xor(den[1], d, 64);
        den[2] += __shfl_xor(den[2], d, 64);
        den[3] += __shfl_xor(den[3], d, 64);
    }
    float r0 = 1.f / den[0], r1 = 1.f / den[1], r2 = 1.f / den[2], r3 = 1.f / den[3];
    int h0 = lane >> 5;
    const float2* hpF = (const float2*)hp1;
    float acc0 = 0.f, acc1 = 0.f;
    for (int base = s0; base < s1; base += 64) {
        int i = base + lane;
        if (i < s1) {
            float4 av = *(const float4*)&a1[(size_t)i * 4];
            float4 al;
            al.x = expf(av.x - m[0]) * r0;
            al.y = expf(av.y - m[1]) * r1;
            al.z = expf(av.z - m[2]) * r2;
            al.w = expf(av.w - m[3]) * r3;
            alf[wv][lane] = al;
        }
        int lim = s1 - base; if (lim > 64) lim = 64;
        for (int k = 0; k < lim; ++k) {
            float4 al = alf[wv][k];
            int s = src_p[base + k];
            float2 u = hpF[(size_t)s * 64 + lane];
            float w0 = (h0 == 0) ? al.x : al.y;
            float w1 = (h0 == 0) ? al.z : al.w;
            acc0 += w0 * u.x;
            acc1 += w1 * u.y;
        }
    }
    float e0 = (acc0 > 0.f) ? acc0 : expm1f(acc0);
    float e1 = (acc1 > 0.f) ? acc1 : expm1f(acc1);
    unsigned short h0s = f2b(e0), h1s = f2b(e1);
    hn1oh[(size_t)w * 128 + lane] = h0s;
    hn1ol[(size_t)w * 128 + lane] = f2b(e0 - b2f(h0s));
    hn1oh[(size_t)w * 128 + 64 + lane] = h1s;
    hn1ol[(size_t)w * 128 + 64 + lane] = f2b(e1 - b2f(h1s));
}

// ---------------- node projections layer2 (split-bf16 MFMA, no LDS) ----------------
// 16 nodes per block (shared A-tile); wave w owns output columns [w*192, w*192+192)
__global__ __launch_bounds__(256) void k_nodeproj2(
        const unsigned short* __restrict__ hn1oh, const unsigned short* __restrict__ hn1ol,
        const unsigned short* __restrict__ W2h, const unsigned short* __restrict__ W2l,
        const float* __restrict__ b2,
        float* __restrict__ hp2, float* __restrict__ pa2, float* __restrict__ pc2) {
    int tid = threadIdx.x;
    int w = tid >> 6, l = tid & 63;
    int c = l & 15, g = l >> 4;
    int pb = blockIdx.x * 16;

    f32x4 acc[12];
#pragma unroll
    for (int t = 0; t < 12; ++t) acc[t] = (f32x4)(0.f);

#pragma unroll
    for (int kk = 0; kk < 4; ++kk) {
        int arow = pb + c;
        bf16x8 ah = *(const bf16x8*)&hn1oh[(size_t)arow * 128 + kk * 32 + g * 8];
        bf16x8 al = *(const bf16x8*)&hn1ol[(size_t)arow * 128 + kk * 32 + g * 8];
#pragma unroll
        for (int t = 0; t < 12; ++t) {
            int brow = w * 192 + t * 16 + c;
            bf16x8 bh = *(const bf16x8*)&W2h[(size_t)brow * 128 + kk * 32 + g * 8];
            bf16x8 bl = *(const bf16x8*)&W2l[(size_t)brow * 128 + kk * 32 + g * 8];
            acc[t] = __builtin_amdgcn_mfma_f32_16x16x32_bf16(ah, bh, acc[t], 0, 0, 0);
            acc[t] = __builtin_amdgcn_mfma_f32_16x16x32_bf16(ah, bl, acc[t], 0, 0, 0);
            acc[t] = __builtin_amdgcn_mfma_f32_16x16x32_bf16(al, bh, acc[t], 0, 0, 0);
        }
    }

#pragma unroll
    for (int t = 0; t < 12; ++t) {
        int og = w * 192 + t * 16 + c;
        float bias = (og < 256) ? b2[og] : 0.f;
#pragma unroll
        for (int r = 0; r < 4; ++r) {
            int n = pb + g * 4 + r;
            if (n < NN) store_p2(hp2, pa2, pc2, n, og, acc[t][r] + bias);
        }
    }
}

// ---------------- edge GEMM layer2 (MFMA bf16, CSR order): a2 + heo ----------------
__global__ __launch_bounds__(256) void k_gemm2(
        const unsigned short* __restrict__ he1b, const int* __restrict__ src_p,
        const int* __restrict__ dst_p, const int* __restrict__ eid,
        const unsigned short* __restrict__ W2b, const float* __restrict__ Wa2,
        const float* __restrict__ pa2, const float* __restrict__ pc2,
        float* __restrict__ heo, float* __restrict__ a2) {
    __shared__ float a2l[4 * 64 * 4];
    int tid = threadIdx.x;
    int w = tid >> 6, l = tid & 63;
    int c = l & 15, g = l >> 4;
    int j = w * 16 + c;
    int pb = blockIdx.x * 64;

    f32x4 acc[4][4];
    for (int m = 0; m < 4; ++m)
        for (int t = 0; t < 4; ++t) acc[m][t] = (f32x4)(0.f);

#pragma unroll
    for (int kk = 0; kk < 4; ++kk) {
        bf16x8 b[4];
#pragma unroll
        for (int t = 0; t < 4; ++t)
            b[t] = *(const bf16x8*)&W2b[(size_t)((w + 4 * t) * 16 + c) * 128 + kk * 32 + g * 8];
#pragma unroll
        for (int m = 0; m < 4; ++m) {
            bf16x8 a = *(const bf16x8*)&he1b[(size_t)(pb + m * 16 + c) * 128 + kk * 32 + g * 8];
#pragma unroll
            for (int t = 0; t < 4; ++t)
                acc[m][t] = __builtin_amdgcn_mfma_f32_16x16x32_bf16(a, b[t], acc[m][t], 0, 0, 0);
        }
    }

    float wsj = Wa2[j] + Wa2[64 + j] + Wa2[128 + j] + Wa2[192 + j];
    const float4* paF = (const float4*)pa2;
    const float4* pcF = (const float4*)pc2;

#pragma unroll
    for (int m = 0; m < 4; ++m) {
#pragma unroll
        for (int r = 0; r < 4; ++r) {
            int le = m * 16 + g * 4 + r;
            int pos = pb + le;
            int s = src_p[pos], d = dst_p[pos];
            int e = eid[pos];
            float4 ua = paF[(size_t)s * 64 + j];
            float4 uc = pcF[(size_t)d * 64 + j];
            float f[4];
            f[0] = acc[m][0][r] + ua.x + uc.x;
            f[1] = acc[m][1][r] + ua.y + uc.y;
            f[2] = acc[m][2][r] + ua.z + uc.z;
            f[3] = acc[m][3][r] + ua.w + uc.w;
            float hsum = 0.f;
            float avt[4];
#pragma unroll
            for (int t = 0; t < 4; ++t) {
                float lf = (f[t] > 0.f) ? f[t] : 0.01f * f[t];
                hsum += lf;
                avt[t] = lf * wsj;
            }
#pragma unroll
            for (int t = 0; t < 4; ++t) avt[t] = rowsum16(avt[t]);
            if (c == 15) {
                float4 st = make_float4(avt[0], avt[1], avt[2], avt[3]);
                *(float4*)&a2l[(w * 64 + le) * 4] = st;
            }
            heo[(size_t)e * 64 + j] = 0.25f * hsum;
        }
    }
    __syncthreads();
    {
        int pos = tid >> 2, t = tid & 3;
        float v = a2l[(0 * 64 + pos) * 4 + t] + a2l[(1 * 64 + pos) * 4 + t]
                + a2l[(2 * 64 + pos) * 4 + t] + a2l[(3 * 64 + pos) * 4 + t];
        a2[(size_t)(pb + pos) * 4 + t] = v;
    }
}

// ---------------- segment softmax + aggregate + head-mean, layer2 ----------------
__global__ void k_agg2(const float* __restrict__ a2, const int* __restrict__ off,
                       const int* __restrict__ src_p, const float* __restrict__ hp2,
                       float* __restrict__ hno) {
    __shared__ float4 alf[4][64];
    int wv = threadIdx.x >> 6;
    int w = (blockIdx.x * 256 + threadIdx.x) >> 6;
    int lane = threadIdx.x & 63;
    if (w >= NN) return;
    int s0 = off[w], s1 = off[w + 1];
    if (s1 == s0) {
        hno[(size_t)w * 64 + lane] = 0.f;
        return;
    }
    float m[4] = {-INFINITY, -INFINITY, -INFINITY, -INFINITY};
    for (int i = s0 + lane; i < s1; i += 64) {
        float4 av = *(const float4*)&a2[(size_t)i * 4];
        m[0] = fmaxf(m[0], av.x); m[1] = fmaxf(m[1], av.y);
        m[2] = fmaxf(m[2], av.z); m[3] = fmaxf(m[3], av.w);
    }
#pragma unroll
    for (int d = 1; d < 64; d <<= 1) {
        m[0] = fmaxf(m[0], __shfl_xor(m[0], d, 64));
        m[1] = fmaxf(m[1], __shfl_xor(m[1], d, 64));
        m[2] = fmaxf(m[2], __shfl_xor(m[2], d, 64));
        m[3] = fmaxf(m[3], __shfl_xor(m[3], d, 64));
    }
    float den[4] = {0.f, 0.f, 0.f, 0.f};
    for (int i = s0 + lane; i < s1; i += 64) {
        float4 av = *(const float4*)&a2[(size_t)i * 4];
        den[0] += expf(av.x - m[0]); den[1] += expf(av.y - m[1]);
        den[2] += expf(av.z - m[2]); den[3] += expf(av.w - m[3]);
    }
#pragma unroll
    for (int d = 1; d < 64; d <<= 1) {
        den[0] += __shfl_xor(den[0], d, 64);
        den[1] += __shfl_xor(den[1], d, 64);
        den[2] += __shfl_xor(den[2], d, 64);
        den[3] += __shfl_xor(den[3], d, 64);
    }
    float r0 = 1.f / den[0], r1 = 1.f / den[1], r2 = 1.f / den[2], r3 = 1.f / den[3];
    const float4* hpF = (const float4*)hp2;
    float acc0 = 0.f, acc1 = 0.f, acc2 = 0.f, acc3 = 0.f;
    for (int base = s0; base < s1; base += 64) {
        int i = base + lane;
        if (i < s1) {
            float4 av = *(const float4*)&a2[(size_t)i * 4];
            float4 al;
            al.x = expf(av.x - m[0]) * r0;
            al.y = expf(av.y - m[1]) * r1;
            al.z = expf(av.z - m[2]) * r2;
            al.w = expf(av.w - m[3]) * r3;
            alf[wv][lane] = al;
        }
        int lim = s1 - base; if (lim > 64) lim = 64;
        for (int k = 0; k < lim; ++k) {
            float4 al = alf[wv][k];
            int s = src_p[base + k];
            float4 u = hpF[(size_t)s * 64 + lane];
            acc0 += al.x * u.x;
            acc1 += al.y * u.y;
            acc2 += al.z * u.z;
            acc3 += al.w * u.w;
        }
    }
    hno[(size_t)w * 64 + lane] = 0.25f * (acc0 + acc1 + acc2 + acc3);
}

extern "C" void kernel_launch(void* const* d_in, const int* in_sizes, int n_in,
                              void* d_out, int out_size, void* d_ws, size_t ws_size,
                              hipStream_t stream) {
    const float* efeats = (const float*)d_in[1];
    const int* src = (const int*)d_in[2];
    const int* dst = (const int*)d_in[3];
    const float* Wn1 = (const float*)d_in[4];
    const float* b1  = (const float*)d_in[5];
    const float* We1 = (const float*)d_in[6];
    const float* Wa1 = (const float*)d_in[7];
    const float* Wn2 = (const float*)d_in[8];
    const float* b2  = (const float*)d_in[9];
    const float* We2 = (const float*)d_in[10];
    const float* Wa2 = (const float*)d_in[11];

    const int NNP = 30016;  // NN padded to 16 (1876 blocks of 16 nodes)

    char* ws = (char*)d_ws;
    size_t o = 0;
    auto alloc = [&](size_t bytes) {
        void* p = ws + o;
        o += (bytes + 255) & ~(size_t)255;
        return p;
    };
    int* cnt   = (int*)alloc((size_t)NN * 4);
    int* off   = (int*)alloc((size_t)(NN + 1) * 4);
    int* cur   = (int*)alloc((size_t)NN * 4);
    int* eid   = (int*)alloc((size_t)NE * 4);
    int* src_p = (int*)alloc((size_t)NE * 4);
    int* dst_p = (int*)alloc((size_t)NE * 4);
    int* bsum  = (int*)alloc(64 * 4);
    int* bbase = (int*)alloc(64 * 4);
    float* a1  = (float*)alloc((size_t)NE * 4 * 4);   // reused as a2
    unsigned short* efb_p = (unsigned short*)alloc((size_t)NE * 64 * 2);
    unsigned short* he1b  = (unsigned short*)alloc((size_t)NE * 128 * 2);
    unsigned short* W1b   = (unsigned short*)alloc((size_t)128 * 64 * 2);
    unsigned short* W2b   = (unsigned short*)alloc((size_t)256 * 128 * 2);
    unsigned short* W1h   = (unsigned short*)alloc((size_t)384 * 64 * 2);
    unsigned short* W1l   = (unsigned short*)alloc((size_t)384 * 64 * 2);
    unsigned short* W2h   = (unsigned short*)alloc((size_t)768 * 128 * 2);
    unsigned short* W2l   = (unsigned short*)alloc((size_t)768 * 128 * 2);
    unsigned short* hn1h  = (unsigned short*)alloc((size_t)NNP * 64 * 2);
    unsigned short* hn1l  = (unsigned short*)alloc((size_t)NNP * 64 * 2);
    unsigned short* hn1oh = (unsigned short*)alloc((size_t)NNP * 128 * 2);
    unsigned short* hn1ol = (unsigned short*)alloc((size_t)NNP * 128 * 2);
    float* hp1   = (float*)alloc((size_t)NN * 128 * 4);
    float* pa1   = (float*)alloc((size_t)NN * 128 * 4);
    float* pc1   = (float*)alloc((size_t)NN * 128 * 4);
    float* hp2   = (float*)alloc((size_t)NN * 256 * 4);
    float* pa2   = (float*)alloc((size_t)NN * 256 * 4);
    float* pc2   = (float*)alloc((size_t)NN * 256 * 4);

    float* hno = (float*)d_out;
    float* heo = (float*)d_out + (size_t)NN * 64;

    const int SCAN_B = (NN + 1023) / 1024;
    const int NPB = NNP / 16;  // 1876
    hipMemsetAsync(cnt, 0, (size_t)NN * 4, stream);
    k_count<<<(NE + 255) / 256, 256, 0, stream>>>(dst, cnt);
    k_scanA<<<SCAN_B, 1024, 0, stream>>>(cnt, off, bsum);
    k_scanB<<<1, 64, 0, stream>>>(bsum, bbase, SCAN_B);
    k_scanC<<<SCAN_B, 1024, 0, stream>>>(off, cur, bbase);
    k_fill<<<(NE + 255) / 256, 256, 0, stream>>>(dst, cur, eid);
    k_convw<<<(128 * 64 + 256 * 128 + 255) / 256, 256, 0, stream>>>(We1, We2, W1b, W2b);
    k_convsplit<<<(384 * 64 + 768 * 128 + 255) / 256, 256, 0, stream>>>(
        Wn1, We1, Wn2, We2, W1h, W1l, W2h, W2l);
    k_perm<<<NE * 8 / 256, 256, 0, stream>>>(efeats, eid, src, dst, efb_p, src_p, dst_p);
    k_agg_ef<<<NN / 4, 256, 0, stream>>>(efeats, off, eid, hn1h, hn1l);
    k_nodeproj1<<<NPB, 256, 0, stream>>>(hn1h, hn1l, W1h, W1l, b1, hp1, pa1, pc1);
    k_gemm1<<<NE / 64, 256, 0, stream>>>(efb_p, src_p, dst_p, W1b, Wa1, pa1, pc1, he1b, a1);
    k_agg1<<<NN / 4, 256, 0, stream>>>(a1, off, src_p, hp1, hn1oh, hn1ol);
    k_nodeproj2<<<NPB, 256, 0, stream>>>(hn1oh, hn1ol, W2h, W2l, b2, hp2, pa2, pc2);
    k_gemm2<<<NE / 64, 256, 0, stream>>>(he1b, src_p, dst_p, eid, W2b, Wa2, pa2, pc2, heo, a1);
    k_agg2<<<NN / 4, 256, 0, stream>>>(a1, off, src_p, hp2, hno);
}

// Round 8
// 758.364 us; speedup vs baseline: 3.4799x; 1.0916x over previous
//
#include <hip/hip_runtime.h>
#include <math.h>

#define NN 30000
#define NE 480000

typedef short bf16x8 __attribute__((ext_vector_type(8)));
typedef float f32x4 __attribute__((ext_vector_type(4)));

static __device__ __forceinline__ unsigned short f2b(float f) {
    union { float f; unsigned u; } v; v.f = f;
    unsigned r = v.u + 0x7FFF + ((v.u >> 16) & 1);
    return (unsigned short)(r >> 16);
}
static __device__ __forceinline__ float b2f(unsigned short s) {
    union { unsigned u; float f; } v; v.u = ((unsigned)s) << 16; return v.f;
}

// Sum across the 16-lane DPP row; lane c==15 holds the full row sum.
static __device__ __forceinline__ float rowsum16(float v) {
    union { float f; int i; } u, t;
    u.f = v;
    t.i = __builtin_amdgcn_update_dpp(0, u.i, 0x111, 0xf, 0xf, true); u.f += t.f;
    t.i = __builtin_amdgcn_update_dpp(0, u.i, 0x112, 0xf, 0xf, true); u.f += t.f;
    t.i = __builtin_amdgcn_update_dpp(0, u.i, 0x114, 0xf, 0xf, true); u.f += t.f;
    t.i = __builtin_amdgcn_update_dpp(0, u.i, 0x118, 0xf, 0xf, true); u.f += t.f;
    return u.f;
}

// ---------------- CSR build (by dst) ----------------
__global__ void k_count(const int* __restrict__ dst, int* __restrict__ cnt) {
    int e = blockIdx.x * 256 + threadIdx.x;
    if (e < NE) atomicAdd(&cnt[dst[e]], 1);
}

__global__ __launch_bounds__(1024) void k_scanA(const int* __restrict__ cnt,
                                                int* __restrict__ off,
                                                int* __restrict__ bsum) {
    __shared__ int s[1024];
    int tid = threadIdx.x;
    int i = blockIdx.x * 1024 + tid;
    int v = (i < NN) ? cnt[i] : 0;
    s[tid] = v;
    __syncthreads();
    for (int d = 1; d < 1024; d <<= 1) {
        int t = (tid >= d) ? s[tid - d] : 0;
        __syncthreads();
        s[tid] += t;
        __syncthreads();
    }
    if (i < NN) off[i] = s[tid] - v;
    if (tid == 1023) bsum[blockIdx.x] = s[1023];
}

__global__ void k_scanB(const int* __restrict__ bsum, int* __restrict__ bbase, int nb) {
    if (threadIdx.x == 0) {
        int run = 0;
        for (int i = 0; i < nb; ++i) { bbase[i] = run; run += bsum[i]; }
    }
}

__global__ __launch_bounds__(1024) void k_scanC(int* __restrict__ off,
                                                int* __restrict__ cur,
                                                const int* __restrict__ bbase) {
    int i = blockIdx.x * 1024 + threadIdx.x;
    if (i < NN) {
        int o = off[i] + bbase[blockIdx.x];
        off[i] = o;
        cur[i] = o;
        if (i == 0) off[NN] = NE;
    }
}

__global__ void k_fill(const int* __restrict__ dst, int* __restrict__ cur,
                       int* __restrict__ eid) {
    int e = blockIdx.x * 256 + threadIdx.x;
    if (e < NE) {
        int p = atomicAdd(&cur[dst[e]], 1);
        eid[p] = e;
    }
}

// ---------------- permute edges into CSR order + convert ef to bf16 ----------------
__global__ void k_perm(const float* __restrict__ ef, const int* __restrict__ eid,
                       const int* __restrict__ src, const int* __restrict__ dst,
                       unsigned short* __restrict__ efb_p, int* __restrict__ src_p,
                       int* __restrict__ dst_p) {
    int gid = blockIdx.x * 256 + threadIdx.x;
    if (gid >= NE * 8) return;
    int i = gid >> 3, sub = gid & 7;
    int e = eid[i];
    if (sub == 0) { src_p[i] = src[e]; dst_p[i] = dst[e]; }
    const float4* p = (const float4*)(ef + (size_t)e * 64 + sub * 8);
    float4 x = p[0], y = p[1];
    uint4 o;
    o.x = (unsigned)f2b(x.x) | ((unsigned)f2b(x.y) << 16);
    o.y = (unsigned)f2b(x.z) | ((unsigned)f2b(x.w) << 16);
    o.z = (unsigned)f2b(y.x) | ((unsigned)f2b(y.y) << 16);
    o.w = (unsigned)f2b(y.z) | ((unsigned)f2b(y.w) << 16);
    *(uint4*)(efb_p + (size_t)i * 64 + sub * 8) = o;
}

// edge-GEMM weights (single bf16)
__global__ void k_convw(const float* __restrict__ We1, const float* __restrict__ We2,
                        unsigned short* __restrict__ W1b, unsigned short* __restrict__ W2b) {
    int i = blockIdx.x * 256 + threadIdx.x;
    if (i < 128 * 64) {
        int r = i >> 6, k = i & 63;
        W1b[i] = f2b(We1[(size_t)r * 192 + 64 + k]);
    } else if (i < 128 * 64 + 256 * 128) {
        int j = i - 128 * 64;
        int r = j >> 7, k = j & 127;
        W2b[j] = f2b(We2[(size_t)r * 384 + 128 + k]);
    }
}

// node-proj weights, split hi/lo bf16.
__global__ void k_convsplit(const float* __restrict__ Wn1, const float* __restrict__ We1,
                            const float* __restrict__ Wn2, const float* __restrict__ We2,
                            unsigned short* __restrict__ W1h, unsigned short* __restrict__ W1l,
                            unsigned short* __restrict__ W2h, unsigned short* __restrict__ W2l) {
    int i = blockIdx.x * 256 + threadIdx.x;
    if (i < 384 * 64) {
        int r = i >> 6, k = i & 63;
        float v;
        if (r < 128)      v = Wn1[(size_t)r * 64 + k];
        else if (r < 256) v = We1[(size_t)(r - 128) * 192 + k];
        else              v = We1[(size_t)(r - 256) * 192 + 128 + k];
        unsigned short h = f2b(v);
        W1h[i] = h; W1l[i] = f2b(v - b2f(h));
    } else if (i < 384 * 64 + 768 * 128) {
        int j = i - 384 * 64;
        int r = j >> 7, k = j & 127;
        float v;
        if (r < 256)      v = Wn2[(size_t)r * 128 + k];
        else if (r < 512) v = We2[(size_t)(r - 256) * 384 + k];
        else              v = We2[(size_t)(r - 512) * 384 + 256 + k];
        unsigned short h = f2b(v);
        W2h[j] = h; W2l[j] = f2b(v - b2f(h));
    }
}

// ---------------- layer1: hn1 = sum of in-edge feats (fp32 gather) -> hi/lo bf16 ----------------
__global__ void k_agg_ef(const float* __restrict__ ef, const int* __restrict__ off,
                         const int* __restrict__ eid,
                         unsigned short* __restrict__ hn1h, unsigned short* __restrict__ hn1l) {
    int w = (blockIdx.x * 256 + threadIdx.x) >> 6;
    int lane = threadIdx.x & 63;
    if (w >= NN) return;
    int s0 = off[w], s1 = off[w + 1];
    float acc = 0.f;
    int i = s0;
    for (; i + 2 <= s1; i += 2) {
        int e0 = eid[i], e1 = eid[i + 1];
        float v0 = ef[(size_t)e0 * 64 + lane];
        float v1 = ef[(size_t)e1 * 64 + lane];
        acc += v0;
        acc += v1;
    }
    for (; i < s1; ++i) {
        int e = eid[i];
        acc += ef[(size_t)e * 64 + lane];
    }
    unsigned short h = f2b(acc);
    hn1h[(size_t)w * 64 + lane] = h;
    hn1l[(size_t)w * 64 + lane] = f2b(acc - b2f(h));
}

// ---------------- fp32 table store helpers (interleaved layouts for gathers) ----------------
static __device__ __forceinline__ void store_p1(float* hp1, float* pa1,
                                                float* pc1, int n, int o, float v) {
    if (o < 128) {
        hp1[(size_t)n * 128 + (o & 63) * 2 + (o >> 6)] = v;
    } else if (o < 256) {
        int x = o - 128;
        pa1[(size_t)n * 128 + ((x >> 5) * 16 + (x & 15)) * 2 + ((x >> 4) & 1)] = v;
    } else {
        int x = o - 256;
        pc1[(size_t)n * 128 + ((x >> 5) * 16 + (x & 15)) * 2 + ((x >> 4) & 1)] = v;
    }
}

static __device__ __forceinline__ void store_p2(float* hp2, float* pa2,
                                                float* pc2, int n, int o, float v) {
    if (o < 256) {
        hp2[(size_t)n * 256 + (o & 63) * 4 + (o >> 6)] = v;
    } else if (o < 512) {
        int x = o - 256;
        pa2[(size_t)n * 256 + (x & 63) * 4 + (x >> 6)] = v;
    } else {
        int x = o - 512;
        pc2[(size_t)n * 256 + (x & 63) * 4 + (x >> 6)] = v;
    }
}

// ---------------- node projections layer1 (split-bf16 MFMA, no LDS) ----------------
__global__ __launch_bounds__(256) void k_nodeproj1(
        const unsigned short* __restrict__ hn1h, const unsigned short* __restrict__ hn1l,
        const unsigned short* __restrict__ W1h, const unsigned short* __restrict__ W1l,
        const float* __restrict__ b1,
        float* __restrict__ hp1, float* __restrict__ pa1, float* __restrict__ pc1) {
    int tid = threadIdx.x;
    int w = tid >> 6, l = tid & 63;
    int c = l & 15, g = l >> 4;
    int pb = blockIdx.x * 16;

    f32x4 acc[6];
#pragma unroll
    for (int t = 0; t < 6; ++t) acc[t] = (f32x4)(0.f);

#pragma unroll
    for (int kk = 0; kk < 2; ++kk) {
        int arow = pb + c;
        bf16x8 ah = *(const bf16x8*)&hn1h[(size_t)arow * 64 + kk * 32 + g * 8];
        bf16x8 al = *(const bf16x8*)&hn1l[(size_t)arow * 64 + kk * 32 + g * 8];
#pragma unroll
        for (int t = 0; t < 6; ++t) {
            int brow = w * 96 + t * 16 + c;
            bf16x8 bh = *(const bf16x8*)&W1h[(size_t)brow * 64 + kk * 32 + g * 8];
            bf16x8 bl = *(const bf16x8*)&W1l[(size_t)brow * 64 + kk * 32 + g * 8];
            acc[t] = __builtin_amdgcn_mfma_f32_16x16x32_bf16(ah, bh, acc[t], 0, 0, 0);
            acc[t] = __builtin_amdgcn_mfma_f32_16x16x32_bf16(ah, bl, acc[t], 0, 0, 0);
            acc[t] = __builtin_amdgcn_mfma_f32_16x16x32_bf16(al, bh, acc[t], 0, 0, 0);
        }
    }

#pragma unroll
    for (int t = 0; t < 6; ++t) {
        int og = w * 96 + t * 16 + c;
        float bias = (og < 128) ? b1[og] : 0.f;
#pragma unroll
        for (int r = 0; r < 4; ++r) {
            int n = pb + g * 4 + r;
            if (n < NN) store_p1(hp1, pa1, pc1, n, og, acc[t][r] + bias);
        }
    }
}

// ---------------- edge GEMM layer1 (MFMA bf16, CSR order, batched gathers) ----------------
__global__ __launch_bounds__(256) void k_gemm1(
        const unsigned short* __restrict__ efb_p, const int* __restrict__ src_p,
        const int* __restrict__ dst_p, const unsigned short* __restrict__ W1b,
        const float* __restrict__ Wa1, const float* __restrict__ pa1,
        const float* __restrict__ pc1,
        unsigned short* __restrict__ he1b, float* __restrict__ a1) {
    int tid = threadIdx.x;
    int w = tid >> 6, l = tid & 63;
    int c = l & 15, g = l >> 4;
    int pb = blockIdx.x * 64;

    f32x4 acc[4][2];
    for (int m = 0; m < 4; ++m)
        for (int t = 0; t < 2; ++t) acc[m][t] = (f32x4)(0.f);

#pragma unroll
    for (int kk = 0; kk < 2; ++kk) {
        bf16x8 b[2];
#pragma unroll
        for (int t = 0; t < 2; ++t)
            b[t] = *(const bf16x8*)&W1b[(size_t)((2 * w + t) * 16 + c) * 64 + kk * 32 + g * 8];
#pragma unroll
        for (int m = 0; m < 4; ++m) {
            bf16x8 a = *(const bf16x8*)&efb_p[(size_t)(pb + m * 16 + c) * 64 + kk * 32 + g * 8];
#pragma unroll
            for (int t = 0; t < 2; ++t)
                acc[m][t] = __builtin_amdgcn_mfma_f32_16x16x32_bf16(a, b[t], acc[m][t], 0, 0, 0);
        }
    }

    float wsj0 = Wa1[c] + Wa1[32 + c] + Wa1[64 + c] + Wa1[96 + c];
    float wsj1 = Wa1[16 + c] + Wa1[48 + c] + Wa1[80 + c] + Wa1[112 + c];
    const float2* paF = (const float2*)pa1;
    const float2* pcF = (const float2*)pc1;

    int ss[16], dd[16];
#pragma unroll
    for (int m = 0; m < 4; ++m) {
        int4 s4 = *(const int4*)&src_p[pb + m * 16 + g * 4];
        int4 d4 = *(const int4*)&dst_p[pb + m * 16 + g * 4];
        ss[m * 4 + 0] = s4.x; ss[m * 4 + 1] = s4.y; ss[m * 4 + 2] = s4.z; ss[m * 4 + 3] = s4.w;
        dd[m * 4 + 0] = d4.x; dd[m * 4 + 1] = d4.y; dd[m * 4 + 2] = d4.z; dd[m * 4 + 3] = d4.w;
    }

#pragma unroll
    for (int m = 0; m < 4; ++m) {
        float2 ua[4], uc[4];
#pragma unroll
        for (int r = 0; r < 4; ++r) {
            ua[r] = paF[(size_t)ss[m * 4 + r] * 64 + w * 16 + c];
            uc[r] = pcF[(size_t)dd[m * 4 + r] * 64 + w * 16 + c];
        }
#pragma unroll
        for (int r = 0; r < 4; ++r) {
            int pos = pb + m * 16 + g * 4 + r;
            float f0 = acc[m][0][r] + ua[r].x + uc[r].x;
            float f1 = acc[m][1][r] + ua[r].y + uc[r].y;
            float lf0 = (f0 > 0.f) ? f0 : 0.01f * f0;
            float lf1 = (f1 > 0.f) ? f1 : 0.01f * f1;
            float av = lf0 * wsj0 + lf1 * wsj1;
            he1b[(size_t)pos * 128 + w * 32 + c]      = f2b((lf0 > 0.f) ? lf0 : expm1f(lf0));
            he1b[(size_t)pos * 128 + w * 32 + 16 + c] = f2b((lf1 > 0.f) ? lf1 : expm1f(lf1));
            av = rowsum16(av);
            if (c == 15) a1[(size_t)pos * 4 + w] = av;
        }
    }
}

// ---------------- segment softmax + weighted aggregate, layer1 -> hi/lo bf16 ----------------
__global__ void k_agg1(const float* __restrict__ a1, const int* __restrict__ off,
                       const int* __restrict__ src_p, const float* __restrict__ hp1,
                       unsigned short* __restrict__ hn1oh, unsigned short* __restrict__ hn1ol) {
    __shared__ float4 alf[4][64];
    int wv = threadIdx.x >> 6;
    int w = (blockIdx.x * 256 + threadIdx.x) >> 6;
    int lane = threadIdx.x & 63;
    if (w >= NN) return;
    int s0 = off[w], s1 = off[w + 1];
    if (s1 == s0) {
        hn1oh[(size_t)w * 128 + lane] = 0; hn1oh[(size_t)w * 128 + 64 + lane] = 0;
        hn1ol[(size_t)w * 128 + lane] = 0; hn1ol[(size_t)w * 128 + 64 + lane] = 0;
        return;
    }
    float m[4] = {-INFINITY, -INFINITY, -INFINITY, -INFINITY};
    for (int i = s0 + lane; i < s1; i += 64) {
        float4 av = *(const float4*)&a1[(size_t)i * 4];
        m[0] = fmaxf(m[0], av.x); m[1] = fmaxf(m[1], av.y);
        m[2] = fmaxf(m[2], av.z); m[3] = fmaxf(m[3], av.w);
    }
#pragma unroll
    for (int d = 1; d < 64; d <<= 1) {
        m[0] = fmaxf(m[0], __shfl_xor(m[0], d, 64));
        m[1] = fmaxf(m[1], __shfl_xor(m[1], d, 64));
        m[2] = fmaxf(m[2], __shfl_xor(m[2], d, 64));
        m[3] = fmaxf(m[3], __shfl_xor(m[3], d, 64));
    }
    float den[4] = {0.f, 0.f, 0.f, 0.f};
    for (int i = s0 + lane; i < s1; i += 64) {
        float4 av = *(const float4*)&a1[(size_t)i * 4];
        den[0] += expf(av.x - m[0]); den[1] += expf(av.y - m[1]);
        den[2] += expf(av.z - m[2]); den[3] += expf(av.w - m[3]);
    }
#pragma unroll
    for (int d = 1; d < 64; d <<= 1) {
        den[0] += __shfl_xor(den[0], d, 64);
        den[1] += __shfl_xor(den[1], d, 64);
        den[2] += __shfl_xor(den[2], d, 64);
        den[3] += __shfl_xor(den[3], d, 64);
    }
    float r0 = 1.f / den[0], r1 = 1.f / den[1], r2 = 1.f / den[2], r3 = 1.f / den[3];
    int h0 = lane >> 5;
    const float2* hpF = (const float2*)hp1;
    float acc0 = 0.f, acc1 = 0.f;
    for (int base = s0; base < s1; base += 64) {
        int i = base + lane;
        if (i < s1) {
            float4 av = *(const float4*)&a1[(size_t)i * 4];
            float4 al;
            al.x = expf(av.x - m[0]) * r0;
            al.y = expf(av.y - m[1]) * r1;
            al.z = expf(av.z - m[2]) * r2;
            al.w = expf(av.w - m[3]) * r3;
            alf[wv][lane] = al;
        }
        int lim = s1 - base; if (lim > 64) lim = 64;
        int k = 0;
        for (; k + 4 <= lim; k += 4) {
            int sA = src_p[base + k], sB = src_p[base + k + 1];
            int sC = src_p[base + k + 2], sD = src_p[base + k + 3];
            float2 uA = hpF[(size_t)sA * 64 + lane];
            float2 uB = hpF[(size_t)sB * 64 + lane];
            float2 uC = hpF[(size_t)sC * 64 + lane];
            float2 uD = hpF[(size_t)sD * 64 + lane];
            float4 aA = alf[wv][k], aB = alf[wv][k + 1];
            float4 aC = alf[wv][k + 2], aD = alf[wv][k + 3];
            float wA0 = (h0 == 0) ? aA.x : aA.y, wA1 = (h0 == 0) ? aA.z : aA.w;
            float wB0 = (h0 == 0) ? aB.x : aB.y, wB1 = (h0 == 0) ? aB.z : aB.w;
            float wC0 = (h0 == 0) ? aC.x : aC.y, wC1 = (h0 == 0) ? aC.z : aC.w;
            float wD0 = (h0 == 0) ? aD.x : aD.y, wD1 = (h0 == 0) ? aD.z : aD.w;
            acc0 += wA0 * uA.x; acc1 += wA1 * uA.y;
            acc0 += wB0 * uB.x; acc1 += wB1 * uB.y;
            acc0 += wC0 * uC.x; acc1 += wC1 * uC.y;
            acc0 += wD0 * uD.x; acc1 += wD1 * uD.y;
        }
        for (; k < lim; ++k) {
            float4 al = alf[wv][k];
            int s = src_p[base + k];
            float2 u = hpF[(size_t)s * 64 + lane];
            float w0 = (h0 == 0) ? al.x : al.y;
            float w1 = (h0 == 0) ? al.z : al.w;
            acc0 += w0 * u.x;
            acc1 += w1 * u.y;
        }
    }
    float e0 = (acc0 > 0.f) ? acc0 : expm1f(acc0);
    float e1 = (acc1 > 0.f) ? acc1 : expm1f(acc1);
    unsigned short h0s = f2b(e0), h1s = f2b(e1);
    hn1oh[(size_t)w * 128 + lane] = h0s;
    hn1ol[(size_t)w * 128 + lane] = f2b(e0 - b2f(h0s));
    hn1oh[(size_t)w * 128 + 64 + lane] = h1s;
    hn1ol[(size_t)w * 128 + 64 + lane] = f2b(e1 - b2f(h1s));
}

// ---------------- node projections layer2 (split-bf16 MFMA, no LDS) ----------------
__global__ __launch_bounds__(256) void k_nodeproj2(
        const unsigned short* __restrict__ hn1oh, const unsigned short* __restrict__ hn1ol,
        const unsigned short* __restrict__ W2h, const unsigned short* __restrict__ W2l,
        const float* __restrict__ b2,
        float* __restrict__ hp2, float* __restrict__ pa2, float* __restrict__ pc2) {
    int tid = threadIdx.x;
    int w = tid >> 6, l = tid & 63;
    int c = l & 15, g = l >> 4;
    int pb = blockIdx.x * 16;

    f32x4 acc[12];
#pragma unroll
    for (int t = 0; t < 12; ++t) acc[t] = (f32x4)(0.f);

#pragma unroll
    for (int kk = 0; kk < 4; ++kk) {
        int arow = pb + c;
        bf16x8 ah = *(const bf16x8*)&hn1oh[(size_t)arow * 128 + kk * 32 + g * 8];
        bf16x8 al = *(const bf16x8*)&hn1ol[(size_t)arow * 128 + kk * 32 + g * 8];
#pragma unroll
        for (int t = 0; t < 12; ++t) {
            int brow = w * 192 + t * 16 + c;
            bf16x8 bh = *(const bf16x8*)&W2h[(size_t)brow * 128 + kk * 32 + g * 8];
            bf16x8 bl = *(const bf16x8*)&W2l[(size_t)brow * 128 + kk * 32 + g * 8];
            acc[t] = __builtin_amdgcn_mfma_f32_16x16x32_bf16(ah, bh, acc[t], 0, 0, 0);
            acc[t] = __builtin_amdgcn_mfma_f32_16x16x32_bf16(ah, bl, acc[t], 0, 0, 0);
            acc[t] = __builtin_amdgcn_mfma_f32_16x16x32_bf16(al, bh, acc[t], 0, 0, 0);
        }
    }

#pragma unroll
    for (int t = 0; t < 12; ++t) {
        int og = w * 192 + t * 16 + c;
        float bias = (og < 256) ? b2[og] : 0.f;
#pragma unroll
        for (int r = 0; r < 4; ++r) {
            int n = pb + g * 4 + r;
            if (n < NN) store_p2(hp2, pa2, pc2, n, og, acc[t][r] + bias);
        }
    }
}

// ---------------- edge GEMM layer2 (MFMA bf16, CSR order, batched gathers): a2 + heo ----------------
__global__ __launch_bounds__(256) void k_gemm2(
        const unsigned short* __restrict__ he1b, const int* __restrict__ src_p,
        const int* __restrict__ dst_p, const int* __restrict__ eid,
        const unsigned short* __restrict__ W2b, const float* __restrict__ Wa2,
        const float* __restrict__ pa2, const float* __restrict__ pc2,
        float* __restrict__ heo, float* __restrict__ a2) {
    __shared__ float a2l[4 * 64 * 4];
    int tid = threadIdx.x;
    int w = tid >> 6, l = tid & 63;
    int c = l & 15, g = l >> 4;
    int j = w * 16 + c;
    int pb = blockIdx.x * 64;

    f32x4 acc[4][4];
    for (int m = 0; m < 4; ++m)
        for (int t = 0; t < 4; ++t) acc[m][t] = (f32x4)(0.f);

#pragma unroll
    for (int kk = 0; kk < 4; ++kk) {
        bf16x8 b[4];
#pragma unroll
        for (int t = 0; t < 4; ++t)
            b[t] = *(const bf16x8*)&W2b[(size_t)((w + 4 * t) * 16 + c) * 128 + kk * 32 + g * 8];
#pragma unroll
        for (int m = 0; m < 4; ++m) {
            bf16x8 a = *(const bf16x8*)&he1b[(size_t)(pb + m * 16 + c) * 128 + kk * 32 + g * 8];
#pragma unroll
            for (int t = 0; t < 4; ++t)
                acc[m][t] = __builtin_amdgcn_mfma_f32_16x16x32_bf16(a, b[t], acc[m][t], 0, 0, 0);
        }
    }

    float wsj = Wa2[j] + Wa2[64 + j] + Wa2[128 + j] + Wa2[192 + j];
    const float4* paF = (const float4*)pa2;
    const float4* pcF = (const float4*)pc2;

    int ss[16], dd[16];
#pragma unroll
    for (int m = 0; m < 4; ++m) {
        int4 s4 = *(const int4*)&src_p[pb + m * 16 + g * 4];
        int4 d4 = *(const int4*)&dst_p[pb + m * 16 + g * 4];
        ss[m * 4 + 0] = s4.x; ss[m * 4 + 1] = s4.y; ss[m * 4 + 2] = s4.z; ss[m * 4 + 3] = s4.w;
        dd[m * 4 + 0] = d4.x; dd[m * 4 + 1] = d4.y; dd[m * 4 + 2] = d4.z; dd[m * 4 + 3] = d4.w;
    }

#pragma unroll
    for (int m = 0; m < 4; ++m) {
        float4 ua[4], uc[4];
#pragma unroll
        for (int r = 0; r < 4; ++r) {
            ua[r] = paF[(size_t)ss[m * 4 + r] * 64 + j];
            uc[r] = pcF[(size_t)dd[m * 4 + r] * 64 + j];
        }
        int4 e4 = *(const int4*)&eid[pb + m * 16 + g * 4];
        int ee[4] = {e4.x, e4.y, e4.z, e4.w};
#pragma unroll
        for (int r = 0; r < 4; ++r) {
            int le = m * 16 + g * 4 + r;
            float f[4];
            f[0] = acc[m][0][r] + ua[r].x + uc[r].x;
            f[1] = acc[m][1][r] + ua[r].y + uc[r].y;
            f[2] = acc[m][2][r] + ua[r].z + uc[r].z;
            f[3] = acc[m][3][r] + ua[r].w + uc[r].w;
            float hsum = 0.f;
            float avt[4];
#pragma unroll
            for (int t = 0; t < 4; ++t) {
                float lf = (f[t] > 0.f) ? f[t] : 0.01f * f[t];
                hsum += lf;
                avt[t] = lf * wsj;
            }
#pragma unroll
            for (int t = 0; t < 4; ++t) avt[t] = rowsum16(avt[t]);
            if (c == 15) {
                float4 st = make_float4(avt[0], avt[1], avt[2], avt[3]);
                *(float4*)&a2l[(w * 64 + le) * 4] = st;
            }
            heo[(size_t)ee[r] * 64 + j] = 0.25f * hsum;
        }
    }
    __syncthreads();
    {
        int pos = tid >> 2, t = tid & 3;
        float v = a2l[(0 * 64 + pos) * 4 + t] + a2l[(1 * 64 + pos) * 4 + t]
                + a2l[(2 * 64 + pos) * 4 + t] + a2l[(3 * 64 + pos) * 4 + t];
        a2[(size_t)(pb + pos) * 4 + t] = v;
    }
}

// ---------------- segment softmax + aggregate + head-mean, layer2 ----------------
__global__ void k_agg2(const float* __restrict__ a2, const int* __restrict__ off,
                       const int* __restrict__ src_p, const float* __restrict__ hp2,
                       float* __restrict__ hno) {
    __shared__ float4 alf[4][64];
    int wv = threadIdx.x >> 6;
    int w = (blockIdx.x * 256 + threadIdx.x) >> 6;
    int lane = threadIdx.x & 63;
    if (w >= NN) return;
    int s0 = off[w], s1 = off[w + 1];
    if (s1 == s0) {
        hno[(size_t)w * 64 + lane] = 0.f;
        return;
    }
    float m[4] = {-INFINITY, -INFINITY, -INFINITY, -INFINITY};
    for (int i = s0 + lane; i < s1; i += 64) {
        float4 av = *(const float4*)&a2[(size_t)i * 4];
        m[0] = fmaxf(m[0], av.x); m[1] = fmaxf(m[1], av.y);
        m[2] = fmaxf(m[2], av.z); m[3] = fmaxf(m[3], av.w);
    }
#pragma unroll
    for (int d = 1; d < 64; d <<= 1) {
        m[0] = fmaxf(m[0], __shfl_xor(m[0], d, 64));
        m[1] = fmaxf(m[1], __shfl_xor(m[1], d, 64));
        m[2] = fmaxf(m[2], __shfl_xor(m[2], d, 64));
        m[3] = fmaxf(m[3], __shfl_xor(m[3], d, 64));
    }
    float den[4] = {0.f, 0.f, 0.f, 0.f};
    for (int i = s0 + lane; i < s1; i += 64) {
        float4 av = *(const float4*)&a2[(size_t)i * 4];
        den[0] += expf(av.x - m[0]); den[1] += expf(av.y - m[1]);
        den[2] += expf(av.z - m[2]); den[3] += expf(av.w - m[3]);
    }
#pragma unroll
    for (int d = 1; d < 64; d <<= 1) {
        den[0] += __shfl_xor(den[0], d, 64);
        den[1] += __shfl_xor(den[1], d, 64);
        den[2] += __shfl_xor(den[2], d, 64);
        den[3] += __shfl_xor(den[3], d, 64);
    }
    float r0 = 1.f / den[0], r1 = 1.f / den[1], r2 = 1.f / den[2], r3 = 1.f / den[3];
    const float4* hpF = (const float4*)hp2;
    float acc0 = 0.f, acc1 = 0.f, acc2 = 0.f, acc3 = 0.f;
    for (int base = s0; base < s1; base += 64) {
        int i = base + lane;
        if (i < s1) {
            float4 av = *(const float4*)&a2[(size_t)i * 4];
            float4 al;
            al.x = expf(av.x - m[0]) * r0;
            al.y = expf(av.y - m[1]) * r1;
            al.z = expf(av.z - m[2]) * r2;
            al.w = expf(av.w - m[3]) * r3;
            alf[wv][lane] = al;
        }
        int lim = s1 - base; if (lim > 64) lim = 64;
        int k = 0;
        for (; k + 4 <= lim; k += 4) {
            int sA = src_p[base + k], sB = src_p[base + k + 1];
            int sC = src_p[base + k + 2], sD = src_p[base + k + 3];
            float4 uA = hpF[(size_t)sA * 64 + lane];
            float4 uB = hpF[(size_t)sB * 64 + lane];
            float4 uC = hpF[(size_t)sC * 64 + lane];
            float4 uD = hpF[(size_t)sD * 64 + lane];
            float4 aA = alf[wv][k], aB = alf[wv][k + 1];
            float4 aC = alf[wv][k + 2], aD = alf[wv][k + 3];
            acc0 += aA.x * uA.x; acc1 += aA.y * uA.y; acc2 += aA.z * uA.z; acc3 += aA.w * uA.w;
            acc0 += aB.x * uB.x; acc1 += aB.y * uB.y; acc2 += aB.z * uB.z; acc3 += aB.w * uB.w;
            acc0 += aC.x * uC.x; acc1 += aC.y * uC.y; acc2 += aC.z * uC.z; acc3 += aC.w * uC.w;
            acc0 += aD.x * uD.x; acc1 += aD.y * uD.y; acc2 += aD.z * uD.z; acc3 += aD.w * uD.w;
        }
        for (; k < lim; ++k) {
            float4 al = alf[wv][k];
            int s = src_p[base + k];
            float4 u = hpF[(size_t)s * 64 + lane];
            acc0 += al.x * u.x;
            acc1 += al.y * u.y;
            acc2 += al.z * u.z;
            acc3 += al.w * u.w;
        }
    }
    hno[(size_t)w * 64 + lane] = 0.25f * (acc0 + acc1 + acc2 + acc3);
}

extern "C" void kernel_launch(void* const* d_in, const int* in_sizes, int n_in,
                              void* d_out, int out_size, void* d_ws, size_t ws_size,
                              hipStream_t stream) {
    const float* efeats = (const float*)d_in[1];
    const int* src = (const int*)d_in[2];
    const int* dst = (const int*)d_in[3];
    const float* Wn1 = (const float*)d_in[4];
    const float* b1  = (const float*)d_in[5];
    const float* We1 = (const float*)d_in[6];
    const float* Wa1 = (const float*)d_in[7];
    const float* Wn2 = (const float*)d_in[8];
    const float* b2  = (const float*)d_in[9];
    const float* We2 = (const float*)d_in[10];
    const float* Wa2 = (const float*)d_in[11];

    const int NNP = 30016;  // NN padded to 16 (1876 blocks of 16 nodes)

    char* ws = (char*)d_ws;
    size_t o = 0;
    auto alloc = [&](size_t bytes) {
        void* p = ws + o;
        o += (bytes + 255) & ~(size_t)255;
        return p;
    };
    int* cnt   = (int*)alloc((size_t)NN * 4);
    int* off   = (int*)alloc((size_t)(NN + 1) * 4);
    int* cur   = (int*)alloc((size_t)NN * 4);
    int* eid   = (int*)alloc((size_t)NE * 4);
    int* src_p = (int*)alloc((size_t)NE * 4);
    int* dst_p = (int*)alloc((size_t)NE * 4);
    int* bsum  = (int*)alloc(64 * 4);
    int* bbase = (int*)alloc(64 * 4);
    float* a1  = (float*)alloc((size_t)NE * 4 * 4);   // reused as a2
    unsigned short* efb_p = (unsigned short*)alloc((size_t)NE * 64 * 2);
    unsigned short* he1b  = (unsigned short*)alloc((size_t)NE * 128 * 2);
    unsigned short* W1b   = (unsigned short*)alloc((size_t)128 * 64 * 2);
    unsigned short* W2b   = (unsigned short*)alloc((size_t)256 * 128 * 2);
    unsigned short* W1h   = (unsigned short*)alloc((size_t)384 * 64 * 2);
    unsigned short* W1l   = (unsigned short*)alloc((size_t)384 * 64 * 2);
    unsigned short* W2h   = (unsigned short*)alloc((size_t)768 * 128 * 2);
    unsigned short* W2l   = (unsigned short*)alloc((size_t)768 * 128 * 2);
    unsigned short* hn1h  = (unsigned short*)alloc((size_t)NNP * 64 * 2);
    unsigned short* hn1l  = (unsigned short*)alloc((size_t)NNP * 64 * 2);
    unsigned short* hn1oh = (unsigned short*)alloc((size_t)NNP * 128 * 2);
    unsigned short* hn1ol = (unsigned short*)alloc((size_t)NNP * 128 * 2);
    float* hp1   = (float*)alloc((size_t)NN * 128 * 4);
    float* pa1   = (float*)alloc((size_t)NN * 128 * 4);
    float* pc1   = (float*)alloc((size_t)NN * 128 * 4);
    float* hp2   = (float*)alloc((size_t)NN * 256 * 4);
    float* pa2   = (float*)alloc((size_t)NN * 256 * 4);
    float* pc2   = (float*)alloc((size_t)NN * 256 * 4);

    float* hno = (float*)d_out;
    float* heo = (float*)d_out + (size_t)NN * 64;

    const int SCAN_B = (NN + 1023) / 1024;
    const int NPB = NNP / 16;  // 1876
    hipMemsetAsync(cnt, 0, (size_t)NN * 4, stream);
    k_count<<<(NE + 255) / 256, 256, 0, stream>>>(dst, cnt);
    k_scanA<<<SCAN_B, 1024, 0, stream>>>(cnt, off, bsum);
    k_scanB<<<1, 64, 0, stream>>>(bsum, bbase, SCAN_B);
    k_scanC<<<SCAN_B, 1024, 0, stream>>>(off, cur, bbase);
    k_fill<<<(NE + 255) / 256, 256, 0, stream>>>(dst, cur, eid);
    k_convw<<<(128 * 64 + 256 * 128 + 255) / 256, 256, 0, stream>>>(We1, We2, W1b, W2b);
    k_convsplit<<<(384 * 64 + 768 * 128 + 255) / 256, 256, 0, stream>>>(
        Wn1, We1, Wn2, We2, W1h, W1l, W2h, W2l);
    k_perm<<<NE * 8 / 256, 256, 0, stream>>>(efeats, eid, src, dst, efb_p, src_p, dst_p);
    k_agg_ef<<<NN / 4, 256, 0, stream>>>(efeats, off, eid, hn1h, hn1l);
    k_nodeproj1<<<NPB, 256, 0, stream>>>(hn1h, hn1l, W1h, W1l, b1, hp1, pa1, pc1);
    k_gemm1<<<NE / 64, 256, 0, stream>>>(efb_p, src_p, dst_p, W1b, Wa1, pa1, pc1, he1b, a1);
    k_agg1<<<NN / 4, 256, 0, stream>>>(a1, off, src_p, hp1, hn1oh, hn1ol);
    k_nodeproj2<<<NPB, 256, 0, stream>>>(hn1oh, hn1ol, W2h, W2l, b2, hp2, pa2, pc2);
    k_gemm2<<<NE / 64, 256, 0, stream>>>(he1b, src_p, dst_p, eid, W2b, Wa2, pa2, pc2, heo, a1);
    k_agg2<<<NN / 4, 256, 0, stream>>>(a1, off, src_p, hp2, hno);
}